// Round 1
// baseline (280.713 us; speedup 1.0000x reference)
//
#include <hip/hip_runtime.h>

#define NEGV (-1.0e9f)

typedef __bf16 bf16_t;
typedef __bf16 bf16x8 __attribute__((ext_vector_type(8)));
typedef __bf16 bf16x4 __attribute__((ext_vector_type(4)));
typedef float  f32x4  __attribute__((ext_vector_type(4)));

// async global->LDS, 16B per lane; LDS dest is wave-uniform base + lane*16
__device__ __forceinline__ void gld16(const void* g, void* l) {
    __builtin_amdgcn_global_load_lds(
        (const __attribute__((address_space(1))) void*)g,
        (__attribute__((address_space(3))) void*)l, 16, 0, 0);
}

// ---------------------------------------------------------------------------
// 256x256 NT MFMA mainloop, BK=64, 512 threads = 8 waves (2 M-half x 4 N-quad),
// per-wave 128x64 output (acc[8][4]).  C[256,256] = A[256,K] x B[256,K]^T,
// both operands row-major k-contiguous.
//
// LDS (128 KiB): A dbuf 2x32KB @ [0,64K), B dbuf 2x32KB @ [64K,128K).
// Layout per tile: rows 0..255, 8 chunks of 16B per row; phys chunk p of row r
// holds LOGICAL chunk p ^ (r&7)  (full 8-slot XOR -> 32-bank-balanced
// ds_read_b128 fragment reads).  Staged with LINEAR LDS dest (global_load_lds
// requirement) + inverse-swizzled GLOBAL source (rule: both-sides-or-neither).
//
// Schedule: 4 quadrant phases per K-tile, quadrant = (h = i-half, kk = k-slice).
// Each phase: 8x ds_read_b128 (frags) || 2x global_load_lds (1 half-tile of
// K-tile kt+1 into the other buffer) -> s_barrier -> lgkmcnt(0) ->
// setprio(1) + 16 MFMA + setprio(0) -> barrier.  ONE vmcnt(0) per K-tile
// (end of phase 3): staging loads stay in flight 1-4 MFMA phases across
// barriers instead of draining every 16 MFMAs.
// Hazards: reads of buf X finish (per-phase lgkmcnt0 + barrier) before any
// wave stages into X again (2 tiles later); tile-end vmcnt0+barrier makes all
// waves' stage parts of buf X' globally visible before X' is read.
// ---------------------------------------------------------------------------

#define STG(P0, P1, BASE, NB, HOFS) do {               \
    gld16(P0, (BASE) + (NB) * 32768 + (HOFS));         \
    gld16(P1, (BASE) + (NB) * 32768 + (HOFS) + 8192);  \
    P0 += 64; P1 += 64; } while (0)

#define MMROW(ai)                                                                                    \
    acc[ib + ai][0] = __builtin_amdgcn_mfma_f32_16x16x32_bf16(a##ai, b0, acc[ib + ai][0], 0, 0, 0);  \
    acc[ib + ai][1] = __builtin_amdgcn_mfma_f32_16x16x32_bf16(a##ai, b1, acc[ib + ai][1], 0, 0, 0);  \
    acc[ib + ai][2] = __builtin_amdgcn_mfma_f32_16x16x32_bf16(a##ai, b2, acc[ib + ai][2], 0, 0, 0);  \
    acc[ib + ai][3] = __builtin_amdgcn_mfma_f32_16x16x32_bf16(a##ai, b3, acc[ib + ai][3], 0, 0, 0)

#define PHASE(BUFO, HOFS, PK, STAGE_STMT, ENDW) do {                     \
    bf16x8 a0 = *(const bf16x8*)(rdA + (BUFO) + (HOFS)        + (PK));   \
    bf16x8 a1 = *(const bf16x8*)(rdA + (BUFO) + (HOFS) + 2048 + (PK));   \
    bf16x8 a2 = *(const bf16x8*)(rdA + (BUFO) + (HOFS) + 4096 + (PK));   \
    bf16x8 a3 = *(const bf16x8*)(rdA + (BUFO) + (HOFS) + 6144 + (PK));   \
    bf16x8 b0 = *(const bf16x8*)(rdB + (BUFO)          + (PK));          \
    bf16x8 b1 = *(const bf16x8*)(rdB + (BUFO) + 2048   + (PK));          \
    bf16x8 b2 = *(const bf16x8*)(rdB + (BUFO) + 4096   + (PK));          \
    bf16x8 b3 = *(const bf16x8*)(rdB + (BUFO) + 6144   + (PK));          \
    STAGE_STMT;                                                          \
    __builtin_amdgcn_s_barrier();                                        \
    asm volatile("s_waitcnt lgkmcnt(0)" ::: "memory");                   \
    __builtin_amdgcn_s_setprio(1);                                       \
    {                                                                    \
        const int ib = (HOFS) ? 4 : 0;                                   \
        MMROW(0); MMROW(1); MMROW(2); MMROW(3);                          \
    }                                                                    \
    __builtin_amdgcn_s_setprio(0);                                       \
    ENDW;                                                                \
    __builtin_amdgcn_s_barrier();                                        \
} while (0)

__device__ __forceinline__ void mainloop256(
    const bf16_t* __restrict__ A, const bf16_t* __restrict__ B,
    int ldA, int ldB, int nkt, char* smem, int tid, f32x4 acc[8][4])
{
    const int w    = tid >> 6;
    const int lane = tid & 63;
    const int wm   = w & 1;     // M half: rows wm*128..+128
    const int wn   = w >> 1;    // N quarter: cols wn*64..+64
    const int l16  = lane & 15;
    const int quad = lane >> 4;

    // staging map: slot s = u*512 + tid -> LDS row s>>3, phys chunk s&7;
    // global source supplies logical chunk (s&7)^(row&7) (pre-swizzle).
    const int r0 = tid >> 3;
    const int c0 = ((tid & 7) ^ (r0 & 7)) * 8;
    const int s1 = 512 + tid;
    const int r1 = s1 >> 3;
    const int c1 = ((s1 & 7) ^ (r1 & 7)) * 8;

    const bf16_t* pa00 = A + (size_t)(r0)       * ldA + c0;
    const bf16_t* pa01 = A + (size_t)(r1)       * ldA + c1;
    const bf16_t* pa10 = A + (size_t)(128 + r0) * ldA + c0;
    const bf16_t* pa11 = A + (size_t)(128 + r1) * ldA + c1;
    const bf16_t* pb00 = B + (size_t)(r0)       * ldB + c0;
    const bf16_t* pb01 = B + (size_t)(r1)       * ldB + c1;
    const bf16_t* pb10 = B + (size_t)(128 + r0) * ldB + c0;
    const bf16_t* pb11 = B + (size_t)(128 + r1) * ldB + c1;

    // LDS staging bases (wave-uniform; HW adds lane*16): slot byte = s*16
    char* const stA = smem + (w << 10);
    char* const stB = smem + 65536 + (w << 10);

    // fragment read: row R, logical chunk kk*4+quad -> phys ^ (R&7); R&7 == l16&7
    const int pk0 = ((quad    ) ^ (l16 & 7)) << 4;
    const int pk1 = ((quad + 4) ^ (l16 & 7)) << 4;
    const char* rdA = smem +         ((wm << 7) + l16) * 128;
    const char* rdB = smem + 65536 + ((wn << 6) + l16) * 128;

    // prologue: stage tile 0 into buffer 0
    STG(pa00, pa01, stA, 0, 0);
    STG(pa10, pa11, stA, 0, 16384);
    STG(pb00, pb01, stB, 0, 0);
    STG(pb10, pb11, stB, 0, 16384);
    asm volatile("s_waitcnt vmcnt(0)" ::: "memory");
    __builtin_amdgcn_s_barrier();

    for (int kt = 0; kt < nkt; ++kt) {
        const int bufo = (kt & 1) << 15;   // read buffer byte offset
        const int nb   = (kt & 1) ^ 1;     // stage buffer index
        const bool st  = (kt + 1) < nkt;
        PHASE(bufo, 0,    pk0, if (st) STG(pa00, pa01, stA, nb, 0),     );
        PHASE(bufo, 0,    pk1, if (st) STG(pa10, pa11, stA, nb, 16384), );
        PHASE(bufo, 8192, pk0, if (st) STG(pb00, pb01, stB, nb, 0),     );
        PHASE(bufo, 8192, pk1, if (st) STG(pb10, pb11, stB, nb, 16384),
              asm volatile("s_waitcnt vmcnt(0)" ::: "memory"));
    }
}

// ---------------------------------------------------------------------------
__global__ __launch_bounds__(256)
void convert_x_kernel(const float* __restrict__ x, bf16_t* __restrict__ xb)
{
    const size_t i = ((size_t)blockIdx.x * 256 + threadIdx.x) * 8;
    float4 a = *(const float4*)&x[i];
    float4 b = *(const float4*)&x[i + 4];
    bf16x8 o;
    o[0] = (bf16_t)a.x; o[1] = (bf16_t)a.y; o[2] = (bf16_t)a.z; o[3] = (bf16_t)a.w;
    o[4] = (bf16_t)b.x; o[5] = (bf16_t)b.y; o[6] = (bf16_t)b.z; o[7] = (bf16_t)b.w;
    *(bf16x8*)&xb[i] = o;
}

// All three W [1024x1024] fp32 -> WT bf16 transposed, z selects matrix
__global__ __launch_bounds__(256)
void transpose_w_kernel(const float* __restrict__ W0, const float* __restrict__ W1,
                        const float* __restrict__ W2, bf16_t* __restrict__ WT)
{
    __shared__ float t[32][33];
    const float* W = (blockIdx.z == 0) ? W0 : (blockIdx.z == 1) ? W1 : W2;
    bf16_t* WTz = WT + (size_t)blockIdx.z * 1024 * 1024;
    const int k0 = blockIdx.y * 32, n0 = blockIdx.x * 32;
    const int r = threadIdx.x >> 3, c4 = (threadIdx.x & 7) * 4;
    float4 v = *(const float4*)&W[(size_t)(k0 + r) * 1024 + n0 + c4];
    t[r][c4 + 0] = v.x; t[r][c4 + 1] = v.y; t[r][c4 + 2] = v.z; t[r][c4 + 3] = v.w;
    __syncthreads();
    bf16x4 o;
#pragma unroll
    for (int j = 0; j < 4; ++j) o[j] = (bf16_t)t[c4 + j][r];
    *(bf16x4*)&WTz[(size_t)(n0 + r) * 1024 + k0 + c4] = o;
}

// ---------------------------------------------------------------------------
// QK projection: C[M,2048] bf16 = xb[M,1024] x WT[2048,1024]^T + (bq|bk)
// 256 blocks = exactly 1/CU; bijective XCD chunking: each XCD gets 4
// contiguous m-panels (2MB A in its L2) + full WT.
// ---------------------------------------------------------------------------
__global__ __launch_bounds__(512, 2)
void gemm_qk256(const bf16_t* __restrict__ A, const bf16_t* __restrict__ Bt,
                const float* __restrict__ bq, const float* __restrict__ bk,
                bf16_t* __restrict__ C, int N, int Kd)
{
    __shared__ __align__(16) char smem[131072];
    int bid = blockIdx.y * 8 + blockIdx.x;          // 256 blocks
    bid = (bid & 7) * 32 + (bid >> 3);              // XCD chunking (256%8==0)
    const int n0 = (bid & 7) * 256;
    const int m0 = (bid >> 3) * 256;
    const int tid = threadIdx.x;

    f32x4 acc[8][4];
#pragma unroll
    for (int i = 0; i < 8; ++i)
#pragma unroll
        for (int j = 0; j < 4; ++j) acc[i][j] = (f32x4)(0.0f);

    mainloop256(A + (size_t)m0 * Kd, Bt + (size_t)n0 * Kd, Kd, Kd, Kd >> 6,
                smem, tid, acc);

    const int w = tid >> 6, lane = tid & 63;
    const int wm = w & 1, wn = w >> 1, quad = lane >> 4, l16 = lane & 15;
#pragma unroll
    for (int j = 0; j < 4; ++j) {
        const int col = n0 + wn * 64 + j * 16 + l16;
        const float bval = (col < 1024) ? bq[col] : bk[col - 1024];
#pragma unroll
        for (int i = 0; i < 8; ++i) {
            const int row = m0 + wm * 128 + i * 16 + quad * 4;
#pragma unroll
            for (int r = 0; r < 4; ++r)
                C[(size_t)(row + r) * N + col] = (bf16_t)(acc[i][j][r] + bval);
        }
    }
}

// ---------------------------------------------------------------------------
// V^T projection: VT[1024, 8192] bf16 = WvT[1024,1024] x xb[8192,1024]^T + bv
// ---------------------------------------------------------------------------
__global__ __launch_bounds__(512, 2)
void gemm_vt256(const bf16_t* __restrict__ WvT, const bf16_t* __restrict__ xb,
                const float* __restrict__ bv, bf16_t* __restrict__ VT,
                int N, int Kd)
{
    __shared__ __align__(16) char smem[131072];
    const int m0 = blockIdx.y * 256, n0 = blockIdx.x * 256;
    const int tid = threadIdx.x;

    f32x4 acc[8][4];
#pragma unroll
    for (int i = 0; i < 8; ++i)
#pragma unroll
        for (int j = 0; j < 4; ++j) acc[i][j] = (f32x4)(0.0f);

    mainloop256(WvT + (size_t)m0 * Kd, xb + (size_t)n0 * Kd, Kd, Kd, Kd >> 6,
                smem, tid, acc);

    const int w = tid >> 6, lane = tid & 63;
    const int wm = w & 1, wn = w >> 1, quad = lane >> 4, l16 = lane & 15;
#pragma unroll
    for (int i = 0; i < 8; ++i) {
        const int row = m0 + wm * 128 + i * 16 + quad * 4;    // d index
#pragma unroll
        for (int r = 0; r < 4; ++r) {
            const float bval = bv[row + r];
#pragma unroll
            for (int j = 0; j < 4; ++j) {
                const int col = n0 + wn * 64 + j * 16 + l16;  // b*L + l
                VT[(size_t)(row + r) * N + col] = (bf16_t)(acc[i][j][r] + bval);
            }
        }
    }
}

// ---------------------------------------------------------------------------
// Scores, triangular-only: blockIdx.x in [0,36) -> (it,jt) at 256 granularity.
// ---------------------------------------------------------------------------
__global__ __launch_bounds__(512, 2)
void scores256(const bf16_t* __restrict__ Q, const bf16_t* __restrict__ K,
               int ldq, const int* __restrict__ lengths,
               float* __restrict__ S, int L, int Dd, float alpha)
{
    __shared__ __align__(16) char smem[131072];
    const int b = blockIdx.z;
    const int len = lengths[b];
    int it = 0;
    while ((it + 1) * (it + 2) / 2 <= (int)blockIdx.x) ++it;
    const int jt = blockIdx.x - it * (it + 1) / 2;
    const int m0 = it * 256, n0 = jt * 256;
    float* Sb = S + (size_t)b * L * L;
    const int tid = threadIdx.x;

    f32x4 acc[8][4];
#pragma unroll
    for (int i = 0; i < 8; ++i)
#pragma unroll
        for (int j = 0; j < 4; ++j) acc[i][j] = (f32x4)(0.0f);

    const bf16_t* Qb = Q + (size_t)b * L * ldq + (size_t)m0 * ldq;
    const bf16_t* Kb = K + (size_t)b * L * ldq + (size_t)n0 * ldq;
    mainloop256(Qb, Kb, ldq, ldq, Dd >> 6, smem, tid, acc);

    const int w = tid >> 6, lane = tid & 63;
    const int wm = w & 1, wn = w >> 1, quad = lane >> 4, l16 = lane & 15;
#pragma unroll
    for (int i = 0; i < 8; ++i) {
#pragma unroll
        for (int j = 0; j < 4; ++j) {
            const int col = n0 + wn * 64 + j * 16 + l16;
#pragma unroll
            for (int r = 0; r < 4; ++r) {
                const int row = m0 + wm * 128 + i * 16 + quad * 4 + r;
                float s = acc[i][j][r] * alpha;
                if (col > row) s += NEGV;                 // causal first
                if (row >= len || col >= len) s += NEGV;  // then length mask
                Sb[(size_t)row * L + col] = s;
            }
        }
    }
}

// ---------------------------------------------------------------------------
// Row softmax, causally bounded: values for j<bound (128-aligned), ZEROS for
// j in [bound, bound2) with bound2 256-aligned -- pv256 consumes P in
// 256-row k-extents and must never read garbage.
// ---------------------------------------------------------------------------
__global__ __launch_bounds__(256)
void softmax_kernel(const float* __restrict__ S, bf16_t* __restrict__ P,
                    int L, int ldp)
{
    __shared__ float red[8];
    const int i = blockIdx.x;
    const int bound  = ((i >> 7) + 1) << 7;
    const int bound2 = ((i >> 8) + 1) << 8;
    const float* row = S + ((size_t)blockIdx.y * L + i) * L;
    bf16_t* prow = P + ((size_t)blockIdx.y * L + i) * ldp;
    const int t = threadIdx.x;
    const int w = t >> 6, lane = t & 63;
    const int j8 = t * 8;
    const bool act = j8 < bound;

    float v[8];
    float m = -3.0e38f;
    if (act) {
        float4 a = *(const float4*)&row[j8];
        float4 b = *(const float4*)&row[j8 + 4];
        v[0] = a.x; v[1] = a.y; v[2] = a.z; v[3] = a.w;
        v[4] = b.x; v[5] = b.y; v[6] = b.z; v[7] = b.w;
#pragma unroll
        for (int j = 0; j < 8; ++j) m = fmaxf(m, v[j]);
    }
#pragma unroll
    for (int off = 32; off > 0; off >>= 1) m = fmaxf(m, __shfl_down(m, off, 64));
    if (lane == 0) red[w] = m;
    __syncthreads();
    m = fmaxf(fmaxf(red[0], red[1]), fmaxf(red[2], red[3]));

    float s = 0.f;
    if (act) {
#pragma unroll
        for (int j = 0; j < 8; ++j) {
            v[j] = __expf(v[j] - m);
            s += v[j];
        }
    }
#pragma unroll
    for (int off = 32; off > 0; off >>= 1) s += __shfl_down(s, off, 64);
    if (lane == 0) red[4 + w] = s;
    __syncthreads();
    s = red[4] + red[5] + red[6] + red[7];

    if (act) {
        const float inv = 1.0f / s;
        bf16x8 o;
#pragma unroll
        for (int j = 0; j < 8; ++j) o[j] = (bf16_t)(v[j] * inv);
        *(bf16x8*)&prow[j8] = o;
    } else if (j8 < bound2) {
        bf16x8 z;
#pragma unroll
        for (int j = 0; j < 8; ++j) z[j] = (bf16_t)0.0f;
        *(bf16x8*)&prow[j8] = z;
    }
}

// ---------------------------------------------------------------------------
// PV: O[b][L,D] fp32 = P[b][L,L] x V^T (VT layout [d][b][l], ld 8192),
// causal k-limit at 256 granularity, heavy tiles dispatched first.
// ---------------------------------------------------------------------------
__global__ __launch_bounds__(512, 2)
void pv256(const bf16_t* __restrict__ P, int ldp,
           const bf16_t* __restrict__ VT, int ldv,
           float* __restrict__ O, int L, int Dd)
{
    __shared__ __align__(16) char smem[131072];
    const int b = blockIdx.z;
    const int mt = gridDim.y - 1 - blockIdx.y;   // heavy first
    const int m0 = mt * 256, n0 = blockIdx.x * 256;
    const int tid = threadIdx.x;

    f32x4 acc[8][4];
#pragma unroll
    for (int i = 0; i < 8; ++i)
#pragma unroll
        for (int j = 0; j < 4; ++j) acc[i][j] = (f32x4)(0.0f);

    const int nkt = (m0 + 256) >> 6;   // P[i][j]==0 for j >= roundup(i+1,256)
    const bf16_t* Pb = P + (size_t)b * L * ldp + (size_t)m0 * ldp;
    const bf16_t* Vb = VT + (size_t)b * L + (size_t)n0 * ldv;
    mainloop256(Pb, Vb, ldp, ldv, nkt, smem, tid, acc);

    float* Ob = O + (size_t)b * L * Dd;
    const int w = tid >> 6, lane = tid & 63;
    const int wm = w & 1, wn = w >> 1, quad = lane >> 4, l16 = lane & 15;
#pragma unroll
    for (int i = 0; i < 8; ++i) {
        const int row = m0 + wm * 128 + i * 16 + quad * 4;
#pragma unroll
        for (int j = 0; j < 4; ++j) {
            const int col = n0 + wn * 64 + j * 16 + l16;
#pragma unroll
            for (int r = 0; r < 4; ++r)
                Ob[(size_t)(row + r) * Dd + col] = acc[i][j][r];
        }
    }
}

// ---------------------------------------------------------------------------
extern "C" void kernel_launch(void* const* d_in, const int* in_sizes, int n_in,
                              void* d_out, int out_size, void* d_ws, size_t ws_size,
                              hipStream_t stream)
{
    const float* x  = (const float*)d_in[0];
    const float* Wq = (const float*)d_in[1];
    const float* bq = (const float*)d_in[2];
    const float* Wk = (const float*)d_in[3];
    const float* bk = (const float*)d_in[4];
    const float* Wv = (const float*)d_in[5];
    const float* bv = (const float*)d_in[6];
    const int*  len = (const int*)d_in[7];
    float* out = (float*)d_out;

    const int B = 4, L = 2048, D = 1024;
    const int M = B * L;     // 8192
    const int N2 = 2 * D;    // 2048

    // Workspace (140.5 MB):
    //  xb [8192][1024] bf16 = 16 MB
    //  WT [3072][1024] bf16 = 6 MB   (Wq^T | Wk^T | Wv^T)
    //  QK [8192][2048] bf16 = 32 MB  (cols 0:Q 1024:K; rows reused as P, ld 2048)
    //  VT [1024][8192] bf16 = 16 MB  (layout [d][b][l])
    //  S  [4][2048][2048] fp32 = 64 MB (lower-triangular tiles only)
    bf16_t* xb = (bf16_t*)d_ws;
    bf16_t* WT = xb + (size_t)M * D;
    bf16_t* QK = WT + (size_t)3 * D * D;
    bf16_t* VT = QK + (size_t)M * N2;
    float*  S  = (float*)(VT + (size_t)D * M);
    bf16_t* P  = QK;   // alias: Q,K dead after scores; ld = 2048

    // 1) x -> bf16
    convert_x_kernel<<<(M * D) / 2048, 256, 0, stream>>>(x, xb);

    // 2) all W transposes in one launch
    transpose_w_kernel<<<dim3(32, 32, 3), 256, 0, stream>>>(Wq, Wk, Wv, WT);

    // 3) QK projection (N=2048), 256x256 tiles, 8-phase mainloop
    gemm_qk256<<<dim3(8, 32), 512, 0, stream>>>(xb, WT, bq, bk, QK, N2, D);

    // 4) V^T projection
    gemm_vt256<<<dim3(32, 4), 512, 0, stream>>>(
        WT + (size_t)2 * D * D, xb, bv, VT, M, D);

    // 5) scores, triangular 256-tiles only
    scores256<<<dim3(36, 1, B), 512, 0, stream>>>(
        QK, QK + 1024, N2, len, S, L, D, 0.03125f);

    // 6) bounded softmax -> P (aliased over QK rows), zero-filled to 256 bound
    softmax_kernel<<<dim3(L, B), 256, 0, stream>>>(S, P, L, N2);

    // 7) O = P @ V, causal k-limit, heavy tiles first
    pv256<<<dim3(4, 8, 4), 512, 0, stream>>>(P, N2, VT, M, out, L, D);
}

// Round 2
// 259.932 us; speedup vs baseline: 1.0799x; 1.0799x over previous
//
#include <hip/hip_runtime.h>

#define NEGV (-1.0e9f)

typedef __bf16 bf16_t;
typedef __bf16 bf16x8 __attribute__((ext_vector_type(8)));
typedef __bf16 bf16x4 __attribute__((ext_vector_type(4)));
typedef float  f32x4  __attribute__((ext_vector_type(4)));

// async global->LDS, 16B per lane; LDS dest is wave-uniform base + lane*16
__device__ __forceinline__ void gld16(const void* g, void* l) {
    __builtin_amdgcn_global_load_lds(
        (const __attribute__((address_space(1))) void*)g,
        (__attribute__((address_space(3))) void*)l, 16, 0, 0);
}

// ===========================================================================
// Variant A: 256x256 tile, BK=64, 512 thr = 8 waves (2M x 4N), acc[8][4].
// LDS 128 KiB. 4 phases/K-tile, 16 MFMA each, ONE vmcnt(0) per K-tile.
// Full 8-slot XOR chunk swizzle; staged linear-LDS + pre-swizzled global src.
// ===========================================================================

#define STG(P0, P1, BASE, NB, HOFS) do {               \
    gld16(P0, (BASE) + (NB) * 32768 + (HOFS));         \
    gld16(P1, (BASE) + (NB) * 32768 + (HOFS) + 8192);  \
    P0 += 64; P1 += 64; } while (0)

#define MMROW(ai)                                                                                    \
    acc[ib + ai][0] = __builtin_amdgcn_mfma_f32_16x16x32_bf16(a##ai, b0, acc[ib + ai][0], 0, 0, 0);  \
    acc[ib + ai][1] = __builtin_amdgcn_mfma_f32_16x16x32_bf16(a##ai, b1, acc[ib + ai][1], 0, 0, 0);  \
    acc[ib + ai][2] = __builtin_amdgcn_mfma_f32_16x16x32_bf16(a##ai, b2, acc[ib + ai][2], 0, 0, 0);  \
    acc[ib + ai][3] = __builtin_amdgcn_mfma_f32_16x16x32_bf16(a##ai, b3, acc[ib + ai][3], 0, 0, 0)

#define PHASE(BUFO, HOFS, PK, STAGE_STMT, ENDW) do {                     \
    bf16x8 a0 = *(const bf16x8*)(rdA + (BUFO) + (HOFS)        + (PK));   \
    bf16x8 a1 = *(const bf16x8*)(rdA + (BUFO) + (HOFS) + 2048 + (PK));   \
    bf16x8 a2 = *(const bf16x8*)(rdA + (BUFO) + (HOFS) + 4096 + (PK));   \
    bf16x8 a3 = *(const bf16x8*)(rdA + (BUFO) + (HOFS) + 6144 + (PK));   \
    bf16x8 b0 = *(const bf16x8*)(rdB + (BUFO)          + (PK));          \
    bf16x8 b1 = *(const bf16x8*)(rdB + (BUFO) + 2048   + (PK));          \
    bf16x8 b2 = *(const bf16x8*)(rdB + (BUFO) + 4096   + (PK));          \
    bf16x8 b3 = *(const bf16x8*)(rdB + (BUFO) + 6144   + (PK));          \
    STAGE_STMT;                                                          \
    __builtin_amdgcn_s_barrier();                                        \
    asm volatile("s_waitcnt lgkmcnt(0)" ::: "memory");                   \
    __builtin_amdgcn_s_setprio(1);                                       \
    {                                                                    \
        const int ib = (HOFS) ? 4 : 0;                                   \
        MMROW(0); MMROW(1); MMROW(2); MMROW(3);                          \
    }                                                                    \
    __builtin_amdgcn_s_setprio(0);                                       \
    ENDW;                                                                \
    __builtin_amdgcn_s_barrier();                                        \
} while (0)

__device__ __forceinline__ void mainloop256(
    const bf16_t* __restrict__ A, const bf16_t* __restrict__ B,
    int ldA, int ldB, int nkt, char* smem, int tid, f32x4 acc[8][4])
{
    const int w    = tid >> 6;
    const int lane = tid & 63;
    const int wm   = w & 1;     // M half
    const int wn   = w >> 1;    // N quarter
    const int l16  = lane & 15;
    const int quad = lane >> 4;

    const int r0 = tid >> 3;
    const int c0 = ((tid & 7) ^ (r0 & 7)) * 8;
    const int s1 = 512 + tid;
    const int r1 = s1 >> 3;
    const int c1 = ((s1 & 7) ^ (r1 & 7)) * 8;

    const bf16_t* pa00 = A + (size_t)(r0)       * ldA + c0;
    const bf16_t* pa01 = A + (size_t)(r1)       * ldA + c1;
    const bf16_t* pa10 = A + (size_t)(128 + r0) * ldA + c0;
    const bf16_t* pa11 = A + (size_t)(128 + r1) * ldA + c1;
    const bf16_t* pb00 = B + (size_t)(r0)       * ldB + c0;
    const bf16_t* pb01 = B + (size_t)(r1)       * ldB + c1;
    const bf16_t* pb10 = B + (size_t)(128 + r0) * ldB + c0;
    const bf16_t* pb11 = B + (size_t)(128 + r1) * ldB + c1;

    char* const stA = smem + (w << 10);
    char* const stB = smem + 65536 + (w << 10);

    const int pk0 = ((quad    ) ^ (l16 & 7)) << 4;
    const int pk1 = ((quad + 4) ^ (l16 & 7)) << 4;
    const char* rdA = smem +         ((wm << 7) + l16) * 128;
    const char* rdB = smem + 65536 + ((wn << 6) + l16) * 128;

    STG(pa00, pa01, stA, 0, 0);
    STG(pa10, pa11, stA, 0, 16384);
    STG(pb00, pb01, stB, 0, 0);
    STG(pb10, pb11, stB, 0, 16384);
    asm volatile("s_waitcnt vmcnt(0)" ::: "memory");
    __builtin_amdgcn_s_barrier();

    for (int kt = 0; kt < nkt; ++kt) {
        const int bufo = (kt & 1) << 15;
        const int nb   = (kt & 1) ^ 1;
        const bool st  = (kt + 1) < nkt;
        PHASE(bufo, 0,    pk0, if (st) STG(pa00, pa01, stA, nb, 0),     );
        PHASE(bufo, 0,    pk1, if (st) STG(pa10, pa11, stA, nb, 16384), );
        PHASE(bufo, 8192, pk0, if (st) STG(pb00, pb01, stB, nb, 0),     );
        PHASE(bufo, 8192, pk1, if (st) STG(pb10, pb11, stB, nb, 16384),
              asm volatile("s_waitcnt vmcnt(0)" ::: "memory"));
    }
}

// ===========================================================================
// Variant B: 256x128 tile, BK=64, 512 thr = 8 waves (4M x 2N), acc[4][4].
// LDS 96 KiB (A dbuf 2x32K @ [0,64K), B dbuf 2x16K @ [64K,96K)).
// 2 phases/K-tile (one per k-slice), 16 MFMA each, ONE vmcnt(0) per K-tile.
// Same swizzle + hazard structure as variant A.  Purpose: >=256-block grids
// for the triangular / skinny stages (pv, scores, vt).
// ===========================================================================

#define STG2(P0, P1, DST) do {                                   \
    gld16(P0, (DST)); gld16(P1, (char*)(DST) + 8192);            \
    P0 += 64; P1 += 64; } while (0)

#define MM2ROW(ai)                                                                         \
    acc[ai][0] = __builtin_amdgcn_mfma_f32_16x16x32_bf16(a##ai, b0, acc[ai][0], 0, 0, 0);  \
    acc[ai][1] = __builtin_amdgcn_mfma_f32_16x16x32_bf16(a##ai, b1, acc[ai][1], 0, 0, 0);  \
    acc[ai][2] = __builtin_amdgcn_mfma_f32_16x16x32_bf16(a##ai, b2, acc[ai][2], 0, 0, 0);  \
    acc[ai][3] = __builtin_amdgcn_mfma_f32_16x16x32_bf16(a##ai, b3, acc[ai][3], 0, 0, 0)

#define PHASEX(AOFS, BOFS, PK, STAGE_STMT, ENDW) do {                  \
    bf16x8 a0 = *(const bf16x8*)(rdA + (AOFS)        + (PK));          \
    bf16x8 a1 = *(const bf16x8*)(rdA + (AOFS) + 2048 + (PK));          \
    bf16x8 a2 = *(const bf16x8*)(rdA + (AOFS) + 4096 + (PK));          \
    bf16x8 a3 = *(const bf16x8*)(rdA + (AOFS) + 6144 + (PK));          \
    bf16x8 b0 = *(const bf16x8*)(rdB + (BOFS)        + (PK));          \
    bf16x8 b1 = *(const bf16x8*)(rdB + (BOFS) + 2048 + (PK));          \
    bf16x8 b2 = *(const bf16x8*)(rdB + (BOFS) + 4096 + (PK));          \
    bf16x8 b3 = *(const bf16x8*)(rdB + (BOFS) + 6144 + (PK));          \
    STAGE_STMT;                                                        \
    __builtin_amdgcn_s_barrier();                                      \
    asm volatile("s_waitcnt lgkmcnt(0)" ::: "memory");                 \
    __builtin_amdgcn_s_setprio(1);                                     \
    MM2ROW(0); MM2ROW(1); MM2ROW(2); MM2ROW(3);                        \
    __builtin_amdgcn_s_setprio(0);                                     \
    ENDW;                                                              \
    __builtin_amdgcn_s_barrier();                                      \
} while (0)

__device__ __forceinline__ void mainloop256x128(
    const bf16_t* __restrict__ A, const bf16_t* __restrict__ B,
    int ldA, int ldB, int nkt, char* smem, int tid, f32x4 acc[4][4])
{
    const int w    = tid >> 6;
    const int lane = tid & 63;
    const int wm   = w & 3;     // M quarter: rows wm*64..+64
    const int wn   = w >> 2;    // N half:   cols wn*64..+64
    const int l16  = lane & 15;
    const int quad = lane >> 4;

    const int r0 = tid >> 3;
    const int c0 = ((tid & 7) ^ (r0 & 7)) * 8;
    const int s1 = 512 + tid;
    const int r1 = s1 >> 3;
    const int c1 = ((s1 & 7) ^ (r1 & 7)) * 8;

    const bf16_t* pa00 = A + (size_t)(r0)       * ldA + c0;
    const bf16_t* pa01 = A + (size_t)(r1)       * ldA + c1;
    const bf16_t* pa10 = A + (size_t)(128 + r0) * ldA + c0;
    const bf16_t* pa11 = A + (size_t)(128 + r1) * ldA + c1;
    const bf16_t* pb0  = B + (size_t)(r0)       * ldB + c0;
    const bf16_t* pb1  = B + (size_t)(r1)       * ldB + c1;

    char* const stA = smem + (w << 10);            // + lane*16 by HW
    char* const stB = smem + 65536 + (w << 10);

    const int pk0 = ((quad    ) ^ (l16 & 7)) << 4;
    const int pk1 = ((quad + 4) ^ (l16 & 7)) << 4;
    const char* rdA = smem +         ((wm << 6) + l16) * 128;
    const char* rdB = smem + 65536 + ((wn << 6) + l16) * 128;

    // prologue: tile 0 -> buffer 0
    STG2(pa00, pa01, stA);
    STG2(pa10, pa11, stA + 16384);
    STG2(pb0,  pb1,  stB);
    asm volatile("s_waitcnt vmcnt(0)" ::: "memory");
    __builtin_amdgcn_s_barrier();

    for (int kt = 0; kt < nkt; ++kt) {
        const int aofs = (kt & 1) << 15;                    // A read buf
        const int bofs = (kt & 1) << 14;                    // B read buf
        char* const nA = stA + ((((kt & 1) ^ 1)) << 15);    // A stage buf
        char* const nB = stB + ((((kt & 1) ^ 1)) << 14);    // B stage buf
        const bool st  = (kt + 1) < nkt;
        PHASEX(aofs, bofs, pk0,
               if (st) { STG2(pa00, pa01, nA); STG2(pa10, pa11, nA + 16384); }, );
        PHASEX(aofs, bofs, pk1,
               if (st) { STG2(pb0, pb1, nB); },
               asm volatile("s_waitcnt vmcnt(0)" ::: "memory"));
    }
}

// ---------------------------------------------------------------------------
__global__ __launch_bounds__(256)
void convert_x_kernel(const float* __restrict__ x, bf16_t* __restrict__ xb)
{
    const size_t i = ((size_t)blockIdx.x * 256 + threadIdx.x) * 8;
    float4 a = *(const float4*)&x[i];
    float4 b = *(const float4*)&x[i + 4];
    bf16x8 o;
    o[0] = (bf16_t)a.x; o[1] = (bf16_t)a.y; o[2] = (bf16_t)a.z; o[3] = (bf16_t)a.w;
    o[4] = (bf16_t)b.x; o[5] = (bf16_t)b.y; o[6] = (bf16_t)b.z; o[7] = (bf16_t)b.w;
    *(bf16x8*)&xb[i] = o;
}

// All three W [1024x1024] fp32 -> WT bf16 transposed, z selects matrix
__global__ __launch_bounds__(256)
void transpose_w_kernel(const float* __restrict__ W0, const float* __restrict__ W1,
                        const float* __restrict__ W2, bf16_t* __restrict__ WT)
{
    __shared__ float t[32][33];
    const float* W = (blockIdx.z == 0) ? W0 : (blockIdx.z == 1) ? W1 : W2;
    bf16_t* WTz = WT + (size_t)blockIdx.z * 1024 * 1024;
    const int k0 = blockIdx.y * 32, n0 = blockIdx.x * 32;
    const int r = threadIdx.x >> 3, c4 = (threadIdx.x & 7) * 4;
    float4 v = *(const float4*)&W[(size_t)(k0 + r) * 1024 + n0 + c4];
    t[r][c4 + 0] = v.x; t[r][c4 + 1] = v.y; t[r][c4 + 2] = v.z; t[r][c4 + 3] = v.w;
    __syncthreads();
    bf16x4 o;
#pragma unroll
    for (int j = 0; j < 4; ++j) o[j] = (bf16_t)t[c4 + j][r];
    *(bf16x4*)&WTz[(size_t)(n0 + r) * 1024 + k0 + c4] = o;
}

// ---------------------------------------------------------------------------
// QK projection: C[M,2048] bf16 = xb[M,1024] x WT[2048,1024]^T + (bq|bk)
// 256 blocks = exactly 1/CU, bijective XCD chunking.
// ---------------------------------------------------------------------------
__global__ __launch_bounds__(512, 2)
void gemm_qk256(const bf16_t* __restrict__ A, const bf16_t* __restrict__ Bt,
                const float* __restrict__ bq, const float* __restrict__ bk,
                bf16_t* __restrict__ C, int N, int Kd)
{
    __shared__ __align__(16) char smem[131072];
    int bid = blockIdx.y * 8 + blockIdx.x;          // 256 blocks
    bid = (bid & 7) * 32 + (bid >> 3);              // XCD chunking (256%8==0)
    const int n0 = (bid & 7) * 256;
    const int m0 = (bid >> 3) * 256;
    const int tid = threadIdx.x;

    f32x4 acc[8][4];
#pragma unroll
    for (int i = 0; i < 8; ++i)
#pragma unroll
        for (int j = 0; j < 4; ++j) acc[i][j] = (f32x4)(0.0f);

    mainloop256(A + (size_t)m0 * Kd, Bt + (size_t)n0 * Kd, Kd, Kd, Kd >> 6,
                smem, tid, acc);

    const int w = tid >> 6, lane = tid & 63;
    const int wm = w & 1, wn = w >> 1, quad = lane >> 4, l16 = lane & 15;
#pragma unroll
    for (int j = 0; j < 4; ++j) {
        const int col = n0 + wn * 64 + j * 16 + l16;
        const float bval = (col < 1024) ? bq[col] : bk[col - 1024];
#pragma unroll
        for (int i = 0; i < 8; ++i) {
            const int row = m0 + wm * 128 + i * 16 + quad * 4;
#pragma unroll
            for (int r = 0; r < 4; ++r)
                C[(size_t)(row + r) * N + col] = (bf16_t)(acc[i][j][r] + bval);
        }
    }
}

// ---------------------------------------------------------------------------
// V^T projection: VT[1024, 8192] = WvT[1024,1024] x xb[8192,1024]^T + bv
// 256x128 tiles -> grid 64x4 = 256 blocks (was 128).
// ---------------------------------------------------------------------------
__global__ __launch_bounds__(512, 2)
void gemm_vt256(const bf16_t* __restrict__ WvT, const bf16_t* __restrict__ xb,
                const float* __restrict__ bv, bf16_t* __restrict__ VT,
                int N, int Kd)
{
    __shared__ __align__(16) char smem[98304];
    const int m0 = blockIdx.y * 256;     // d
    const int n0 = blockIdx.x * 128;     // b*L + l
    const int tid = threadIdx.x;

    f32x4 acc[4][4];
#pragma unroll
    for (int i = 0; i < 4; ++i)
#pragma unroll
        for (int j = 0; j < 4; ++j) acc[i][j] = (f32x4)(0.0f);

    mainloop256x128(WvT + (size_t)m0 * Kd, xb + (size_t)n0 * Kd, Kd, Kd, Kd >> 6,
                    smem, tid, acc);

    const int w = tid >> 6, lane = tid & 63;
    const int wm = w & 3, wn = w >> 2, quad = lane >> 4, l16 = lane & 15;
#pragma unroll
    for (int i = 0; i < 4; ++i) {
        const int row = m0 + wm * 64 + i * 16 + quad * 4;    // d index
#pragma unroll
        for (int r = 0; r < 4; ++r) {
            const float bval = bv[row + r];
#pragma unroll
            for (int j = 0; j < 4; ++j) {
                const int col = n0 + wn * 64 + j * 16 + l16;
                VT[(size_t)(row + r) * N + col] = (bf16_t)(acc[i][j][r] + bval);
            }
        }
    }
}

// ---------------------------------------------------------------------------
// Scores: 256-row x 128-col triangular tiles.  Per batch 72 tiles
// (row-tile mt has 2mt+2 col-tiles) -> 288 blocks total.
// ---------------------------------------------------------------------------
__global__ __launch_bounds__(512, 2)
void scores256(const bf16_t* __restrict__ Q, const bf16_t* __restrict__ K,
               int ldq, const int* __restrict__ lengths,
               float* __restrict__ S, int L, int Dd, float alpha)
{
    __shared__ __align__(16) char smem[98304];
    const int b = blockIdx.z;
    const int len = lengths[b];
    int mt = 0;                                   // idx in [mt(mt+1), +2mt+2)
    while ((mt + 1) * (mt + 2) <= (int)blockIdx.x) ++mt;
    const int jt = blockIdx.x - mt * (mt + 1);
    const int m0 = mt * 256, n0 = jt * 128;
    float* Sb = S + (size_t)b * L * L;
    const int tid = threadIdx.x;

    f32x4 acc[4][4];
#pragma unroll
    for (int i = 0; i < 4; ++i)
#pragma unroll
        for (int j = 0; j < 4; ++j) acc[i][j] = (f32x4)(0.0f);

    const bf16_t* Qb = Q + (size_t)b * L * ldq + (size_t)m0 * ldq;
    const bf16_t* Kb = K + (size_t)b * L * ldq + (size_t)n0 * ldq;
    mainloop256x128(Qb, Kb, ldq, ldq, Dd >> 6, smem, tid, acc);

    const int w = tid >> 6, lane = tid & 63;
    const int wm = w & 3, wn = w >> 2, quad = lane >> 4, l16 = lane & 15;
#pragma unroll
    for (int i = 0; i < 4; ++i) {
#pragma unroll
        for (int j = 0; j < 4; ++j) {
            const int col = n0 + wn * 64 + j * 16 + l16;
#pragma unroll
            for (int r = 0; r < 4; ++r) {
                const int row = m0 + wm * 64 + i * 16 + quad * 4 + r;
                float s = acc[i][j][r] * alpha;
                if (col > row) s += NEGV;                 // causal first
                if (row >= len || col >= len) s += NEGV;  // then length mask
                Sb[(size_t)row * L + col] = s;
            }
        }
    }
}

// ---------------------------------------------------------------------------
// Row softmax, causally bounded: values for j<bound (128-aligned), ZEROS for
// j in [bound, bound2) with bound2 256-aligned -- pv consumes P in 256-row
// k-extents and must never read garbage.
// ---------------------------------------------------------------------------
__global__ __launch_bounds__(256)
void softmax_kernel(const float* __restrict__ S, bf16_t* __restrict__ P,
                    int L, int ldp)
{
    __shared__ float red[8];
    const int i = blockIdx.x;
    const int bound  = ((i >> 7) + 1) << 7;
    const int bound2 = ((i >> 8) + 1) << 8;
    const float* row = S + ((size_t)blockIdx.y * L + i) * L;
    bf16_t* prow = P + ((size_t)blockIdx.y * L + i) * ldp;
    const int t = threadIdx.x;
    const int w = t >> 6, lane = t & 63;
    const int j8 = t * 8;
    const bool act = j8 < bound;

    float v[8];
    float m = -3.0e38f;
    if (act) {
        float4 a = *(const float4*)&row[j8];
        float4 b = *(const float4*)&row[j8 + 4];
        v[0] = a.x; v[1] = a.y; v[2] = a.z; v[3] = a.w;
        v[4] = b.x; v[5] = b.y; v[6] = b.z; v[7] = b.w;
#pragma unroll
        for (int j = 0; j < 8; ++j) m = fmaxf(m, v[j]);
    }
#pragma unroll
    for (int off = 32; off > 0; off >>= 1) m = fmaxf(m, __shfl_down(m, off, 64));
    if (lane == 0) red[w] = m;
    __syncthreads();
    m = fmaxf(fmaxf(red[0], red[1]), fmaxf(red[2], red[3]));

    float s = 0.f;
    if (act) {
#pragma unroll
        for (int j = 0; j < 8; ++j) {
            v[j] = __expf(v[j] - m);
            s += v[j];
        }
    }
#pragma unroll
    for (int off = 32; off > 0; off >>= 1) s += __shfl_down(s, off, 64);
    if (lane == 0) red[4 + w] = s;
    __syncthreads();
    s = red[4] + red[5] + red[6] + red[7];

    if (act) {
        const float inv = 1.0f / s;
        bf16x8 o;
#pragma unroll
        for (int j = 0; j < 8; ++j) o[j] = (bf16_t)(v[j] * inv);
        *(bf16x8*)&prow[j8] = o;
    } else if (j8 < bound2) {
        bf16x8 z;
#pragma unroll
        for (int j = 0; j < 8; ++j) z[j] = (bf16_t)0.0f;
        *(bf16x8*)&prow[j8] = z;
    }
}

// ---------------------------------------------------------------------------
// PV: O[b][L,D] fp32 = P[b][L,L] x V^T (VT layout [d][b][l], ld 8192).
// 256(l) x 128(d) tiles -> grid 8x8x4 = 256 blocks (was 128), causal k-limit
// at 256-row granularity, heavy m-tiles dispatched first.
// ---------------------------------------------------------------------------
__global__ __launch_bounds__(512, 2)
void pv256(const bf16_t* __restrict__ P, int ldp,
           const bf16_t* __restrict__ VT, int ldv,
           float* __restrict__ O, int L, int Dd)
{
    __shared__ __align__(16) char smem[98304];
    const int b = blockIdx.z;
    const int mt = gridDim.y - 1 - blockIdx.y;   // heavy first
    const int m0 = mt * 256, n0 = blockIdx.x * 128;
    const int tid = threadIdx.x;

    f32x4 acc[4][4];
#pragma unroll
    for (int i = 0; i < 4; ++i)
#pragma unroll
        for (int j = 0; j < 4; ++j) acc[i][j] = (f32x4)(0.0f);

    const int nkt = (m0 + 256) >> 6;   // P[i][j]==0 for j >= roundup(i+1,256)
    const bf16_t* Pb = P + (size_t)b * L * ldp + (size_t)m0 * ldp;
    const bf16_t* Vb = VT + (size_t)b * L + (size_t)n0 * ldv;
    mainloop256x128(Pb, Vb, ldp, ldv, nkt, smem, tid, acc);

    float* Ob = O + (size_t)b * L * Dd;
    const int w = tid >> 6, lane = tid & 63;
    const int wm = w & 3, wn = w >> 2, quad = lane >> 4, l16 = lane & 15;
#pragma unroll
    for (int i = 0; i < 4; ++i) {
        const int row = m0 + wm * 64 + i * 16 + quad * 4;
#pragma unroll
        for (int j = 0; j < 4; ++j) {
            const int col = n0 + wn * 64 + j * 16 + l16;
#pragma unroll
            for (int r = 0; r < 4; ++r)
                Ob[(size_t)(row + r) * Dd + col] = acc[i][j][r];
        }
    }
}

// ---------------------------------------------------------------------------
extern "C" void kernel_launch(void* const* d_in, const int* in_sizes, int n_in,
                              void* d_out, int out_size, void* d_ws, size_t ws_size,
                              hipStream_t stream)
{
    const float* x  = (const float*)d_in[0];
    const float* Wq = (const float*)d_in[1];
    const float* bq = (const float*)d_in[2];
    const float* Wk = (const float*)d_in[3];
    const float* bk = (const float*)d_in[4];
    const float* Wv = (const float*)d_in[5];
    const float* bv = (const float*)d_in[6];
    const int*  len = (const int*)d_in[7];
    float* out = (float*)d_out;

    const int B = 4, L = 2048, D = 1024;
    const int M = B * L;     // 8192
    const int N2 = 2 * D;    // 2048

    // Workspace (140.5 MB):
    //  xb [8192][1024] bf16 = 16 MB
    //  WT [3072][1024] bf16 = 6 MB   (Wq^T | Wk^T | Wv^T)
    //  QK [8192][2048] bf16 = 32 MB  (cols 0:Q 1024:K; rows reused as P, ld 2048)
    //  VT [1024][8192] bf16 = 16 MB  (layout [d][b][l])
    //  S  [4][2048][2048] fp32 = 64 MB (lower-triangular tiles only)
    bf16_t* xb = (bf16_t*)d_ws;
    bf16_t* WT = xb + (size_t)M * D;
    bf16_t* QK = WT + (size_t)3 * D * D;
    bf16_t* VT = QK + (size_t)M * N2;
    float*  S  = (float*)(VT + (size_t)D * M);
    bf16_t* P  = QK;   // alias: Q,K dead after scores; ld = 2048

    // 1) x -> bf16
    convert_x_kernel<<<(M * D) / 2048, 256, 0, stream>>>(x, xb);

    // 2) all W transposes in one launch
    transpose_w_kernel<<<dim3(32, 32, 3), 256, 0, stream>>>(Wq, Wk, Wv, WT);

    // 3) QK projection (N=2048), 256x256 tiles, 256 blocks
    gemm_qk256<<<dim3(8, 32), 512, 0, stream>>>(xb, WT, bq, bk, QK, N2, D);

    // 4) V^T projection, 256x128 tiles, 256 blocks
    gemm_vt256<<<dim3(64, 4), 512, 0, stream>>>(
        WT + (size_t)2 * D * D, xb, bv, VT, M, D);

    // 5) scores, triangular 256x128 tiles, 288 blocks
    scores256<<<dim3(72, 1, B), 512, 0, stream>>>(
        QK, QK + 1024, N2, len, S, L, D, 0.03125f);

    // 6) bounded softmax -> P (aliased over QK rows), zero-filled to 256 bound
    softmax_kernel<<<dim3(L, B), 256, 0, stream>>>(S, P, L, N2);

    // 7) O = P @ V, causal k-limit, 256 blocks, heavy tiles first
    pv256<<<dim3(8, 8, 4), 512, 0, stream>>>(P, N2, VT, M, out, L, D);
}

// Round 3
// 253.121 us; speedup vs baseline: 1.1090x; 1.0269x over previous
//
#include <hip/hip_runtime.h>

#define NEGV (-1.0e9f)

typedef __bf16 bf16_t;
typedef __bf16 bf16x8 __attribute__((ext_vector_type(8)));
typedef __bf16 bf16x4 __attribute__((ext_vector_type(4)));
typedef float  f32x4  __attribute__((ext_vector_type(4)));

// async global->LDS, 16B per lane; LDS dest is wave-uniform base + lane*16
__device__ __forceinline__ void gld16(const void* g, void* l) {
    __builtin_amdgcn_global_load_lds(
        (const __attribute__((address_space(1))) void*)g,
        (__attribute__((address_space(3))) void*)l, 16, 0, 0);
}

// ===========================================================================
// Variant A: 256x256 tile, BK=64, 512 thr = 8 waves (2M x 4N), acc[8][4].
// LDS 128 KiB. 4 phases/K-tile, 16 MFMA each.
// ALL next-tile staging issued in PHASE 1 (8 gld16/thread); single vmcnt(0)
// at end of phase 4 -> youngest load gets ~3 MFMA phases (~1900 cyc) of
// cover vs HBM ~900 cyc.  Full 8-slot XOR chunk swizzle (linear LDS dest +
// pre-swizzled global source).
// ===========================================================================

#define STG(P0, P1, BASE, NB, HOFS) do {               \
    gld16(P0, (BASE) + (NB) * 32768 + (HOFS));         \
    gld16(P1, (BASE) + (NB) * 32768 + (HOFS) + 8192);  \
    P0 += 64; P1 += 64; } while (0)

#define MMROW(ai)                                                                                    \
    acc[ib + ai][0] = __builtin_amdgcn_mfma_f32_16x16x32_bf16(a##ai, b0, acc[ib + ai][0], 0, 0, 0);  \
    acc[ib + ai][1] = __builtin_amdgcn_mfma_f32_16x16x32_bf16(a##ai, b1, acc[ib + ai][1], 0, 0, 0);  \
    acc[ib + ai][2] = __builtin_amdgcn_mfma_f32_16x16x32_bf16(a##ai, b2, acc[ib + ai][2], 0, 0, 0);  \
    acc[ib + ai][3] = __builtin_amdgcn_mfma_f32_16x16x32_bf16(a##ai, b3, acc[ib + ai][3], 0, 0, 0)

#define PHASE(BUFO, HOFS, PK, STAGE_STMT, ENDW) do {                     \
    bf16x8 a0 = *(const bf16x8*)(rdA + (BUFO) + (HOFS)        + (PK));   \
    bf16x8 a1 = *(const bf16x8*)(rdA + (BUFO) + (HOFS) + 2048 + (PK));   \
    bf16x8 a2 = *(const bf16x8*)(rdA + (BUFO) + (HOFS) + 4096 + (PK));   \
    bf16x8 a3 = *(const bf16x8*)(rdA + (BUFO) + (HOFS) + 6144 + (PK));   \
    bf16x8 b0 = *(const bf16x8*)(rdB + (BUFO)          + (PK));          \
    bf16x8 b1 = *(const bf16x8*)(rdB + (BUFO) + 2048   + (PK));          \
    bf16x8 b2 = *(const bf16x8*)(rdB + (BUFO) + 4096   + (PK));          \
    bf16x8 b3 = *(const bf16x8*)(rdB + (BUFO) + 6144   + (PK));          \
    STAGE_STMT;                                                          \
    __builtin_amdgcn_s_barrier();                                        \
    asm volatile("s_waitcnt lgkmcnt(0)" ::: "memory");                   \
    __builtin_amdgcn_s_setprio(1);                                       \
    {                                                                    \
        const int ib = (HOFS) ? 4 : 0;                                   \
        MMROW(0); MMROW(1); MMROW(2); MMROW(3);                          \
    }                                                                    \
    __builtin_amdgcn_s_setprio(0);                                       \
    ENDW;                                                                \
    __builtin_amdgcn_s_barrier();                                        \
} while (0)

__device__ __forceinline__ void mainloop256(
    const bf16_t* __restrict__ A, const bf16_t* __restrict__ B,
    int ldA, int ldB, int nkt, char* smem, int tid, f32x4 acc[8][4])
{
    const int w    = tid >> 6;
    const int lane = tid & 63;
    const int wm   = w & 1;     // M half
    const int wn   = w >> 1;    // N quarter
    const int l16  = lane & 15;
    const int quad = lane >> 4;

    const int r0 = tid >> 3;
    const int c0 = ((tid & 7) ^ (r0 & 7)) * 8;
    const int s1 = 512 + tid;
    const int r1 = s1 >> 3;
    const int c1 = ((s1 & 7) ^ (r1 & 7)) * 8;

    const bf16_t* pa00 = A + (size_t)(r0)       * ldA + c0;
    const bf16_t* pa01 = A + (size_t)(r1)       * ldA + c1;
    const bf16_t* pa10 = A + (size_t)(128 + r0) * ldA + c0;
    const bf16_t* pa11 = A + (size_t)(128 + r1) * ldA + c1;
    const bf16_t* pb00 = B + (size_t)(r0)       * ldB + c0;
    const bf16_t* pb01 = B + (size_t)(r1)       * ldB + c1;
    const bf16_t* pb10 = B + (size_t)(128 + r0) * ldB + c0;
    const bf16_t* pb11 = B + (size_t)(128 + r1) * ldB + c1;

    char* const stA = smem + (w << 10);
    char* const stB = smem + 65536 + (w << 10);

    const int pk0 = ((quad    ) ^ (l16 & 7)) << 4;
    const int pk1 = ((quad + 4) ^ (l16 & 7)) << 4;
    const char* rdA = smem +         ((wm << 7) + l16) * 128;
    const char* rdB = smem + 65536 + ((wn << 6) + l16) * 128;

    STG(pa00, pa01, stA, 0, 0);
    STG(pa10, pa11, stA, 0, 16384);
    STG(pb00, pb01, stB, 0, 0);
    STG(pb10, pb11, stB, 0, 16384);
    asm volatile("s_waitcnt vmcnt(0)" ::: "memory");
    __builtin_amdgcn_s_barrier();

    for (int kt = 0; kt < nkt; ++kt) {
        const int bufo = (kt & 1) << 15;
        const int nb   = (kt & 1) ^ 1;
        const bool st  = (kt + 1) < nkt;
        PHASE(bufo, 0,    pk0,
              if (st) { STG(pa00, pa01, stA, nb, 0);
                        STG(pa10, pa11, stA, nb, 16384);
                        STG(pb00, pb01, stB, nb, 0);
                        STG(pb10, pb11, stB, nb, 16384); }, );
        PHASE(bufo, 0,    pk1, , );
        PHASE(bufo, 8192, pk0, , );
        PHASE(bufo, 8192, pk1, ,
              asm volatile("s_waitcnt vmcnt(0)" ::: "memory"));
    }
}

// ===========================================================================
// Variant B: 256x128 tile, BK=64, 512 thr = 8 waves (4M x 2N), acc[4][4].
// LDS 96 KiB (A dbuf 2x32K @ [0,64K), B dbuf 2x16K @ [64K,96K)).
// 2 phases/K-tile; ALL staging in phase 1 (6 gld16/thread); single vmcnt(0)
// at end of phase 2 -> ~1.5 phases (~1200 cyc) of cover.
// ===========================================================================

#define STG2(P0, P1, DST) do {                                   \
    gld16(P0, (DST)); gld16(P1, (char*)(DST) + 8192);            \
    P0 += 64; P1 += 64; } while (0)

#define MM2ROW(ai)                                                                         \
    acc[ai][0] = __builtin_amdgcn_mfma_f32_16x16x32_bf16(a##ai, b0, acc[ai][0], 0, 0, 0);  \
    acc[ai][1] = __builtin_amdgcn_mfma_f32_16x16x32_bf16(a##ai, b1, acc[ai][1], 0, 0, 0);  \
    acc[ai][2] = __builtin_amdgcn_mfma_f32_16x16x32_bf16(a##ai, b2, acc[ai][2], 0, 0, 0);  \
    acc[ai][3] = __builtin_amdgcn_mfma_f32_16x16x32_bf16(a##ai, b3, acc[ai][3], 0, 0, 0)

#define PHASEX(AOFS, BOFS, PK, STAGE_STMT, ENDW) do {                  \
    bf16x8 a0 = *(const bf16x8*)(rdA + (AOFS)        + (PK));          \
    bf16x8 a1 = *(const bf16x8*)(rdA + (AOFS) + 2048 + (PK));          \
    bf16x8 a2 = *(const bf16x8*)(rdA + (AOFS) + 4096 + (PK));          \
    bf16x8 a3 = *(const bf16x8*)(rdA + (AOFS) + 6144 + (PK));          \
    bf16x8 b0 = *(const bf16x8*)(rdB + (BOFS)        + (PK));          \
    bf16x8 b1 = *(const bf16x8*)(rdB + (BOFS) + 2048 + (PK));          \
    bf16x8 b2 = *(const bf16x8*)(rdB + (BOFS) + 4096 + (PK));          \
    bf16x8 b3 = *(const bf16x8*)(rdB + (BOFS) + 6144 + (PK));          \
    STAGE_STMT;                                                        \
    __builtin_amdgcn_s_barrier();                                      \
    asm volatile("s_waitcnt lgkmcnt(0)" ::: "memory");                 \
    __builtin_amdgcn_s_setprio(1);                                     \
    MM2ROW(0); MM2ROW(1); MM2ROW(2); MM2ROW(3);                        \
    __builtin_amdgcn_s_setprio(0);                                     \
    ENDW;                                                              \
    __builtin_amdgcn_s_barrier();                                      \
} while (0)

__device__ __forceinline__ void mainloop256x128(
    const bf16_t* __restrict__ A, const bf16_t* __restrict__ B,
    int ldA, int ldB, int nkt, char* smem, int tid, f32x4 acc[4][4])
{
    const int w    = tid >> 6;
    const int lane = tid & 63;
    const int wm   = w & 3;     // M quarter: rows wm*64..+64
    const int wn   = w >> 2;    // N half:   cols wn*64..+64
    const int l16  = lane & 15;
    const int quad = lane >> 4;

    const int r0 = tid >> 3;
    const int c0 = ((tid & 7) ^ (r0 & 7)) * 8;
    const int s1 = 512 + tid;
    const int r1 = s1 >> 3;
    const int c1 = ((s1 & 7) ^ (r1 & 7)) * 8;

    const bf16_t* pa00 = A + (size_t)(r0)       * ldA + c0;
    const bf16_t* pa01 = A + (size_t)(r1)       * ldA + c1;
    const bf16_t* pa10 = A + (size_t)(128 + r0) * ldA + c0;
    const bf16_t* pa11 = A + (size_t)(128 + r1) * ldA + c1;
    const bf16_t* pb0  = B + (size_t)(r0)       * ldB + c0;
    const bf16_t* pb1  = B + (size_t)(r1)       * ldB + c1;

    char* const stA = smem + (w << 10);            // + lane*16 by HW
    char* const stB = smem + 65536 + (w << 10);

    const int pk0 = ((quad    ) ^ (l16 & 7)) << 4;
    const int pk1 = ((quad + 4) ^ (l16 & 7)) << 4;
    const char* rdA = smem +         ((wm << 6) + l16) * 128;
    const char* rdB = smem + 65536 + ((wn << 6) + l16) * 128;

    // prologue: tile 0 -> buffer 0
    STG2(pa00, pa01, stA);
    STG2(pa10, pa11, stA + 16384);
    STG2(pb0,  pb1,  stB);
    asm volatile("s_waitcnt vmcnt(0)" ::: "memory");
    __builtin_amdgcn_s_barrier();

    for (int kt = 0; kt < nkt; ++kt) {
        const int aofs = (kt & 1) << 15;                    // A read buf
        const int bofs = (kt & 1) << 14;                    // B read buf
        char* const nA = stA + ((((kt & 1) ^ 1)) << 15);    // A stage buf
        char* const nB = stB + ((((kt & 1) ^ 1)) << 14);    // B stage buf
        const bool st  = (kt + 1) < nkt;
        PHASEX(aofs, bofs, pk0,
               if (st) { STG2(pa00, pa01, nA);
                         STG2(pa10, pa11, nA + 16384);
                         STG2(pb0, pb1, nB); }, );
        PHASEX(aofs, bofs, pk1, ,
               asm volatile("s_waitcnt vmcnt(0)" ::: "memory"));
    }
}

// ---------------------------------------------------------------------------
__global__ __launch_bounds__(256)
void convert_x_kernel(const float* __restrict__ x, bf16_t* __restrict__ xb)
{
    const size_t i = ((size_t)blockIdx.x * 256 + threadIdx.x) * 8;
    float4 a = *(const float4*)&x[i];
    float4 b = *(const float4*)&x[i + 4];
    bf16x8 o;
    o[0] = (bf16_t)a.x; o[1] = (bf16_t)a.y; o[2] = (bf16_t)a.z; o[3] = (bf16_t)a.w;
    o[4] = (bf16_t)b.x; o[5] = (bf16_t)b.y; o[6] = (bf16_t)b.z; o[7] = (bf16_t)b.w;
    *(bf16x8*)&xb[i] = o;
}

// All three W [1024x1024] fp32 -> WT bf16 transposed, z selects matrix
__global__ __launch_bounds__(256)
void transpose_w_kernel(const float* __restrict__ W0, const float* __restrict__ W1,
                        const float* __restrict__ W2, bf16_t* __restrict__ WT)
{
    __shared__ float t[32][33];
    const float* W = (blockIdx.z == 0) ? W0 : (blockIdx.z == 1) ? W1 : W2;
    bf16_t* WTz = WT + (size_t)blockIdx.z * 1024 * 1024;
    const int k0 = blockIdx.y * 32, n0 = blockIdx.x * 32;
    const int r = threadIdx.x >> 3, c4 = (threadIdx.x & 7) * 4;
    float4 v = *(const float4*)&W[(size_t)(k0 + r) * 1024 + n0 + c4];
    t[r][c4 + 0] = v.x; t[r][c4 + 1] = v.y; t[r][c4 + 2] = v.z; t[r][c4 + 3] = v.w;
    __syncthreads();
    bf16x4 o;
#pragma unroll
    for (int j = 0; j < 4; ++j) o[j] = (bf16_t)t[c4 + j][r];
    *(bf16x4*)&WTz[(size_t)(n0 + r) * 1024 + k0 + c4] = o;
}

// ---------------------------------------------------------------------------
// QK projection: C[M,2048] bf16 = xb[M,1024] x WT[2048,1024]^T + (bq|bk)
// 256 blocks = exactly 1/CU, bijective XCD chunking.
// ---------------------------------------------------------------------------
__global__ __launch_bounds__(512, 2)
void gemm_qk256(const bf16_t* __restrict__ A, const bf16_t* __restrict__ Bt,
                const float* __restrict__ bq, const float* __restrict__ bk,
                bf16_t* __restrict__ C, int N, int Kd)
{
    __shared__ __align__(16) char smem[131072];
    int bid = blockIdx.y * 8 + blockIdx.x;          // 256 blocks
    bid = (bid & 7) * 32 + (bid >> 3);              // XCD chunking (256%8==0)
    const int n0 = (bid & 7) * 256;
    const int m0 = (bid >> 3) * 256;
    const int tid = threadIdx.x;

    f32x4 acc[8][4];
#pragma unroll
    for (int i = 0; i < 8; ++i)
#pragma unroll
        for (int j = 0; j < 4; ++j) acc[i][j] = (f32x4)(0.0f);

    mainloop256(A + (size_t)m0 * Kd, Bt + (size_t)n0 * Kd, Kd, Kd, Kd >> 6,
                smem, tid, acc);

    const int w = tid >> 6, lane = tid & 63;
    const int wm = w & 1, wn = w >> 1, quad = lane >> 4, l16 = lane & 15;
#pragma unroll
    for (int j = 0; j < 4; ++j) {
        const int col = n0 + wn * 64 + j * 16 + l16;
        const float bval = (col < 1024) ? bq[col] : bk[col - 1024];
#pragma unroll
        for (int i = 0; i < 8; ++i) {
            const int row = m0 + wm * 128 + i * 16 + quad * 4;
#pragma unroll
            for (int r = 0; r < 4; ++r)
                C[(size_t)(row + r) * N + col] = (bf16_t)(acc[i][j][r] + bval);
        }
    }
}

// ---------------------------------------------------------------------------
// V^T projection: VT[1024, 8192] = WvT[1024,1024] x xb[8192,1024]^T + bv
// 256x128 tiles -> grid 64x4 = 256 blocks, XCD chunking.
// ---------------------------------------------------------------------------
__global__ __launch_bounds__(512, 2)
void gemm_vt256(const bf16_t* __restrict__ WvT, const bf16_t* __restrict__ xb,
                const float* __restrict__ bv, bf16_t* __restrict__ VT,
                int N, int Kd)
{
    __shared__ __align__(16) char smem[98304];
    int bid = blockIdx.y * 64 + blockIdx.x;         // 256 blocks
    bid = (bid & 7) * 32 + (bid >> 3);              // XCD chunking
    const int m0 = (bid >> 6) * 256;     // d
    const int n0 = (bid & 63) * 128;     // b*L + l
    const int tid = threadIdx.x;

    f32x4 acc[4][4];
#pragma unroll
    for (int i = 0; i < 4; ++i)
#pragma unroll
        for (int j = 0; j < 4; ++j) acc[i][j] = (f32x4)(0.0f);

    mainloop256x128(WvT + (size_t)m0 * Kd, xb + (size_t)n0 * Kd, Kd, Kd, Kd >> 6,
                    smem, tid, acc);

    const int w = tid >> 6, lane = tid & 63;
    const int wm = w & 3, wn = w >> 2, quad = lane >> 4, l16 = lane & 15;
#pragma unroll
    for (int i = 0; i < 4; ++i) {
        const int row = m0 + wm * 64 + i * 16 + quad * 4;    // d index
#pragma unroll
        for (int r = 0; r < 4; ++r) {
            const float bval = bv[row + r];
#pragma unroll
            for (int j = 0; j < 4; ++j) {
                const int col = n0 + wn * 64 + j * 16 + l16;
                VT[(size_t)(row + r) * N + col] = (bf16_t)(acc[i][j][r] + bval);
            }
        }
    }
}

// ---------------------------------------------------------------------------
// Scores: 256-row x 128-col triangular tiles.  Per batch 72 tiles
// (row-tile mt has 2mt+2 col-tiles); XCD chunking within batch (72%8==0).
// ---------------------------------------------------------------------------
__global__ __launch_bounds__(512, 2)
void scores256(const bf16_t* __restrict__ Q, const bf16_t* __restrict__ K,
               int ldq, const int* __restrict__ lengths,
               float* __restrict__ S, int L, int Dd, float alpha)
{
    __shared__ __align__(16) char smem[98304];
    const int b = blockIdx.z;
    const int len = lengths[b];
    int tix = (int)blockIdx.x;
    tix = (tix & 7) * 9 + (tix >> 3);             // XCD chunking (72 = 8*9)
    int mt = 0;                                   // idx in [mt(mt+1), +2mt+2)
    while ((mt + 1) * (mt + 2) <= tix) ++mt;
    const int jt = tix - mt * (mt + 1);
    const int m0 = mt * 256, n0 = jt * 128;
    float* Sb = S + (size_t)b * L * L;
    const int tid = threadIdx.x;

    f32x4 acc[4][4];
#pragma unroll
    for (int i = 0; i < 4; ++i)
#pragma unroll
        for (int j = 0; j < 4; ++j) acc[i][j] = (f32x4)(0.0f);

    const bf16_t* Qb = Q + (size_t)b * L * ldq + (size_t)m0 * ldq;
    const bf16_t* Kb = K + (size_t)b * L * ldq + (size_t)n0 * ldq;
    mainloop256x128(Qb, Kb, ldq, ldq, Dd >> 6, smem, tid, acc);

    const int w = tid >> 6, lane = tid & 63;
    const int wm = w & 3, wn = w >> 2, quad = lane >> 4, l16 = lane & 15;
#pragma unroll
    for (int i = 0; i < 4; ++i) {
#pragma unroll
        for (int j = 0; j < 4; ++j) {
            const int col = n0 + wn * 64 + j * 16 + l16;
#pragma unroll
            for (int r = 0; r < 4; ++r) {
                const int row = m0 + wm * 64 + i * 16 + quad * 4 + r;
                float s = acc[i][j][r] * alpha;
                if (col > row) s += NEGV;                 // causal first
                if (row >= len || col >= len) s += NEGV;  // then length mask
                Sb[(size_t)row * L + col] = s;
            }
        }
    }
}

// ---------------------------------------------------------------------------
// Row softmax, causally bounded: values for j<bound (128-aligned), ZEROS for
// j in [bound, bound2) with bound2 256-aligned -- pv consumes P in 256-row
// k-extents and must never read garbage.
// ---------------------------------------------------------------------------
__global__ __launch_bounds__(256)
void softmax_kernel(const float* __restrict__ S, bf16_t* __restrict__ P,
                    int L, int ldp)
{
    __shared__ float red[8];
    const int i = blockIdx.x;
    const int bound  = ((i >> 7) + 1) << 7;
    const int bound2 = ((i >> 8) + 1) << 8;
    const float* row = S + ((size_t)blockIdx.y * L + i) * L;
    bf16_t* prow = P + ((size_t)blockIdx.y * L + i) * ldp;
    const int t = threadIdx.x;
    const int w = t >> 6, lane = t & 63;
    const int j8 = t * 8;
    const bool act = j8 < bound;

    float v[8];
    float m = -3.0e38f;
    if (act) {
        float4 a = *(const float4*)&row[j8];
        float4 b = *(const float4*)&row[j8 + 4];
        v[0] = a.x; v[1] = a.y; v[2] = a.z; v[3] = a.w;
        v[4] = b.x; v[5] = b.y; v[6] = b.z; v[7] = b.w;
#pragma unroll
        for (int j = 0; j < 8; ++j) m = fmaxf(m, v[j]);
    }
#pragma unroll
    for (int off = 32; off > 0; off >>= 1) m = fmaxf(m, __shfl_down(m, off, 64));
    if (lane == 0) red[w] = m;
    __syncthreads();
    m = fmaxf(fmaxf(red[0], red[1]), fmaxf(red[2], red[3]));

    float s = 0.f;
    if (act) {
#pragma unroll
        for (int j = 0; j < 8; ++j) {
            v[j] = __expf(v[j] - m);
            s += v[j];
        }
    }
#pragma unroll
    for (int off = 32; off > 0; off >>= 1) s += __shfl_down(s, off, 64);
    if (lane == 0) red[4 + w] = s;
    __syncthreads();
    s = red[4] + red[5] + red[6] + red[7];

    if (act) {
        const float inv = 1.0f / s;
        bf16x8 o;
#pragma unroll
        for (int j = 0; j < 8; ++j) o[j] = (bf16_t)(v[j] * inv);
        *(bf16x8*)&prow[j8] = o;
    } else if (j8 < bound2) {
        bf16x8 z;
#pragma unroll
        for (int j = 0; j < 8; ++j) z[j] = (bf16_t)0.0f;
        *(bf16x8*)&prow[j8] = z;
    }
}

// ---------------------------------------------------------------------------
// PV: O[b][L,D] fp32 = P[b][L,L] x V^T (VT layout [d][b][l], ld 8192).
// 256(l) x 128(d) tiles -> 256 blocks, causal k-limit at 256-row granularity,
// heavy m-tiles first, XCD chunking within batch (64 = 8*8).
// ---------------------------------------------------------------------------
__global__ __launch_bounds__(512, 2)
void pv256(const bf16_t* __restrict__ P, int ldp,
           const bf16_t* __restrict__ VT, int ldv,
           float* __restrict__ O, int L, int Dd)
{
    __shared__ __align__(16) char smem[98304];
    const int b = blockIdx.z;
    int bid = blockIdx.y * 8 + blockIdx.x;       // 64 per batch
    bid = (bid & 7) * 8 + (bid >> 3);            // XCD chunking
    const int mt = 7 - (bid >> 3);               // heavy first
    const int m0 = mt * 256, n0 = (bid & 7) * 128;
    const int tid = threadIdx.x;

    f32x4 acc[4][4];
#pragma unroll
    for (int i = 0; i < 4; ++i)
#pragma unroll
        for (int j = 0; j < 4; ++j) acc[i][j] = (f32x4)(0.0f);

    const int nkt = (m0 + 256) >> 6;   // P[i][j]==0 for j >= roundup(i+1,256)
    const bf16_t* Pb = P + (size_t)b * L * ldp + (size_t)m0 * ldp;
    const bf16_t* Vb = VT + (size_t)b * L + (size_t)n0 * ldv;
    mainloop256x128(Pb, Vb, ldp, ldv, nkt, smem, tid, acc);

    float* Ob = O + (size_t)b * L * Dd;
    const int w = tid >> 6, lane = tid & 63;
    const int wm = w & 3, wn = w >> 2, quad = lane >> 4, l16 = lane & 15;
#pragma unroll
    for (int i = 0; i < 4; ++i) {
        const int row = m0 + wm * 64 + i * 16 + quad * 4;
#pragma unroll
        for (int j = 0; j < 4; ++j) {
            const int col = n0 + wn * 64 + j * 16 + l16;
#pragma unroll
            for (int r = 0; r < 4; ++r)
                Ob[(size_t)(row + r) * Dd + col] = acc[i][j][r];
        }
    }
}

// ---------------------------------------------------------------------------
extern "C" void kernel_launch(void* const* d_in, const int* in_sizes, int n_in,
                              void* d_out, int out_size, void* d_ws, size_t ws_size,
                              hipStream_t stream)
{
    const float* x  = (const float*)d_in[0];
    const float* Wq = (const float*)d_in[1];
    const float* bq = (const float*)d_in[2];
    const float* Wk = (const float*)d_in[3];
    const float* bk = (const float*)d_in[4];
    const float* Wv = (const float*)d_in[5];
    const float* bv = (const float*)d_in[6];
    const int*  len = (const int*)d_in[7];
    float* out = (float*)d_out;

    const int B = 4, L = 2048, D = 1024;
    const int M = B * L;     // 8192
    const int N2 = 2 * D;    // 2048

    // Workspace (140.5 MB):
    //  xb [8192][1024] bf16 = 16 MB
    //  WT [3072][1024] bf16 = 6 MB   (Wq^T | Wk^T | Wv^T)
    //  QK [8192][2048] bf16 = 32 MB  (cols 0:Q 1024:K; rows reused as P, ld 2048)
    //  VT [1024][8192] bf16 = 16 MB  (layout [d][b][l])
    //  S  [4][2048][2048] fp32 = 64 MB (lower-triangular tiles only)
    bf16_t* xb = (bf16_t*)d_ws;
    bf16_t* WT = xb + (size_t)M * D;
    bf16_t* QK = WT + (size_t)3 * D * D;
    bf16_t* VT = QK + (size_t)M * N2;
    float*  S  = (float*)(VT + (size_t)D * M);
    bf16_t* P  = QK;   // alias: Q,K dead after scores; ld = 2048

    // 1) x -> bf16
    convert_x_kernel<<<(M * D) / 2048, 256, 0, stream>>>(x, xb);

    // 2) all W transposes in one launch
    transpose_w_kernel<<<dim3(32, 32, 3), 256, 0, stream>>>(Wq, Wk, Wv, WT);

    // 3) QK projection (N=2048), 256x256 tiles, 256 blocks
    gemm_qk256<<<dim3(8, 32), 512, 0, stream>>>(xb, WT, bq, bk, QK, N2, D);

    // 4) V^T projection, 256x128 tiles, 256 blocks
    gemm_vt256<<<dim3(64, 4), 512, 0, stream>>>(
        WT + (size_t)2 * D * D, xb, bv, VT, M, D);

    // 5) scores, triangular 256x128 tiles, 288 blocks
    scores256<<<dim3(72, 1, B), 512, 0, stream>>>(
        QK, QK + 1024, N2, len, S, L, D, 0.03125f);

    // 6) bounded softmax -> P (aliased over QK rows), zero-filled to 256 bound
    softmax_kernel<<<dim3(L, B), 256, 0, stream>>>(S, P, L, N2);

    // 7) O = P @ V, causal k-limit, 256 blocks, heavy tiles first
    pv256<<<dim3(8, 8, 4), 512, 0, stream>>>(P, N2, VT, M, out, L, D);
}

// Round 4
// 244.005 us; speedup vs baseline: 1.1504x; 1.0374x over previous
//
#include <hip/hip_runtime.h>

#define NEGV (-1.0e9f)

typedef __bf16 bf16_t;
typedef __bf16 bf16x8 __attribute__((ext_vector_type(8)));
typedef __bf16 bf16x4 __attribute__((ext_vector_type(4)));
typedef float  f32x4  __attribute__((ext_vector_type(4)));

// async global->LDS, 16B per lane; LDS dest is wave-uniform base + lane*16
__device__ __forceinline__ void gld16(const void* g, void* l) {
    __builtin_amdgcn_global_load_lds(
        (const __attribute__((address_space(1))) void*)g,
        (__attribute__((address_space(3))) void*)l, 16, 0, 0);
}

// ===========================================================================
// Triple-buffered counted-vmcnt mainloops (T3+T4), BK=32.
//
// LDS layout per operand tile (rows packed 2-per-128B LDS row):
//   byte(r',h,p) = r'*128 + h*64 + p*16 holds global row (2r'+h),
//   k-chunk c = p ^ (r'&3).  ds_read_b128 fragment reads land 2-way on banks
//   (free, m136); staged with LINEAR LDS dest + inverse-swizzled global src.
//
// Schedule per K-tile kt (ONE barrier per tile):
//   issue ds_reads (buf kt%3) ; stage tile kt+2 -> buf (kt+2)%3 ;
//   lgkmcnt wait ; MFMA ; s_waitcnt vmcnt(4) ; s_barrier
// The counted vmcnt retires tile kt+1's stages and leaves tile kt+2's IN
// FLIGHT across the barrier (never drains to 0 in steady state - m218).
// Hazards: stage target is 2 buffers from read buffer; 1 barrier/tile bounds
// wave drift to 1 tile, and per-tile lgkmcnt(0) retires all reads before the
// barrier, so buf (kt+2)%3's last reads (tile kt-1) precede the stage.
// ===========================================================================

#define MMR(AF, IB)                                                                        \
    acc[IB][0] = __builtin_amdgcn_mfma_f32_16x16x32_bf16(AF, b0, acc[IB][0], 0, 0, 0);     \
    acc[IB][1] = __builtin_amdgcn_mfma_f32_16x16x32_bf16(AF, b1, acc[IB][1], 0, 0, 0);     \
    acc[IB][2] = __builtin_amdgcn_mfma_f32_16x16x32_bf16(AF, b2, acc[IB][2], 0, 0, 0);     \
    acc[IB][3] = __builtin_amdgcn_mfma_f32_16x16x32_bf16(AF, b3, acc[IB][3], 0, 0, 0)

// ---- 256x256 tile, 8 waves (2M x 4N), acc[8][4], LDS 3 x 32K = 96 KiB ----
__device__ __forceinline__ void ml256x256(
    const bf16_t* __restrict__ A, const bf16_t* __restrict__ B,
    int ldA, int ldB, int nkt, char* smem, int tid, f32x4 acc[8][4])
{
    const int w = tid >> 6, lane = tid & 63;
    const int wm = w & 1, wn = w >> 1;
    const int l16 = lane & 15, quad = lane >> 4;

    // staging: slot s=u*512+tid -> LDS byte s*16; global row 2(s>>3)+((s>>2)&1),
    // chunk (s&3)^((s>>3)&3)
    const int g0 = 2 * (tid >> 3) + ((tid >> 2) & 1);
    const int c0 = ((tid & 3) ^ ((tid >> 3) & 3)) * 8;
    const bf16_t* pa0 = A + (size_t)g0 * ldA + c0;
    const bf16_t* pa1 = pa0 + (size_t)128 * ldA;
    const bf16_t* pb0 = B + (size_t)g0 * ldB + c0;
    const bf16_t* pb1 = pb0 + (size_t)128 * ldB;
    char* const stA = smem + (w << 10);           // + u*8192 + buf*32768
    char* const stB = smem + 16384 + (w << 10);

    // fragment read: row R=base+l16: byte (R>>1)*128+(R&1)*64+((quad^((l16>>1)&3))<<4)
    const int rowo = (l16 >> 1) * 128 + (l16 & 1) * 64 + ((quad ^ ((l16 >> 1) & 3)) << 4);
    const char* rdA = smem + (wm << 13) + rowo;            // + i*1024 + bufo
    const char* rdB = smem + 16384 + (wn << 12) + rowo;    // + j*1024 + bufo

#define STG6(BO) do { gld16(pa0, stA + (BO)); gld16(pa1, stA + (BO) + 8192);   \
                      gld16(pb0, stB + (BO)); gld16(pb1, stB + (BO) + 8192);   \
                      pa0 += 32; pa1 += 32; pb0 += 32; pb1 += 32; } while (0)

    STG6(0);                                   // tile 0 -> buf 0
    if (nkt > 1) {
        STG6(32768);                           // tile 1 -> buf 1
        asm volatile("s_waitcnt vmcnt(4)" ::: "memory");   // t0 done, t1 in flight
    } else {
        asm volatile("s_waitcnt vmcnt(0)" ::: "memory");
    }
    __builtin_amdgcn_s_barrier();

    int ro = 0, so = 65536;
    for (int kt = 0; kt < nkt; ++kt) {
        const char* ra = rdA + ro;
        const char* rb = rdB + ro;
        bf16x8 a0 = *(const bf16x8*)(ra);
        bf16x8 a1 = *(const bf16x8*)(ra + 1024);
        bf16x8 a2 = *(const bf16x8*)(ra + 2048);
        bf16x8 a3 = *(const bf16x8*)(ra + 3072);
        bf16x8 b0 = *(const bf16x8*)(rb);
        bf16x8 b1 = *(const bf16x8*)(rb + 1024);
        bf16x8 b2 = *(const bf16x8*)(rb + 2048);
        bf16x8 b3 = *(const bf16x8*)(rb + 3072);
        bf16x8 a4 = *(const bf16x8*)(ra + 4096);
        bf16x8 a5 = *(const bf16x8*)(ra + 5120);
        bf16x8 a6 = *(const bf16x8*)(ra + 6144);
        bf16x8 a7 = *(const bf16x8*)(ra + 7168);
        const bool st = (kt + 2) < nkt;
        if (st) STG6(so);                      // stage tile kt+2
        asm volatile("s_waitcnt lgkmcnt(4)" ::: "memory");  // a0-3,b0-3 ready
        __builtin_amdgcn_sched_barrier(0);
        __builtin_amdgcn_s_setprio(1);
        MMR(a0, 0); MMR(a1, 1); MMR(a2, 2); MMR(a3, 3);
        __builtin_amdgcn_s_setprio(0);
        asm volatile("s_waitcnt lgkmcnt(0)" ::: "memory");  // a4-7 ready
        __builtin_amdgcn_sched_barrier(0);
        __builtin_amdgcn_s_setprio(1);
        MMR(a4, 4); MMR(a5, 5); MMR(a6, 6); MMR(a7, 7);
        __builtin_amdgcn_s_setprio(0);
        if (st) asm volatile("s_waitcnt vmcnt(4)" ::: "memory");  // t_{kt+1} done
        else    asm volatile("s_waitcnt vmcnt(0)" ::: "memory");
        __builtin_amdgcn_s_barrier();
        ro = (ro == 65536) ? 0 : (ro + 32768);
        so = (so == 65536) ? 0 : (so + 32768);
    }
#undef STG6
}

// ---- 256x128 tile, 8 waves (4M x 2N), acc[4][4], LDS 3 x 24K = 72 KiB ----
__device__ __forceinline__ void ml256x128(
    const bf16_t* __restrict__ A, const bf16_t* __restrict__ B,
    int ldA, int ldB, int nkt, char* smem, int tid, f32x4 acc[4][4])
{
    const int w = tid >> 6, lane = tid & 63;
    const int wm = w & 3, wn = w >> 2;
    const int l16 = lane & 15, quad = lane >> 4;

    const int g0 = 2 * (tid >> 3) + ((tid >> 2) & 1);
    const int c0 = ((tid & 3) ^ ((tid >> 3) & 3)) * 8;
    const bf16_t* pa0 = A + (size_t)g0 * ldA + c0;
    const bf16_t* pa1 = pa0 + (size_t)128 * ldA;
    const bf16_t* pb0 = B + (size_t)g0 * ldB + c0;
    char* const stA = smem + (w << 10);
    char* const stB = smem + 16384 + (w << 10);

    const int rowo = (l16 >> 1) * 128 + (l16 & 1) * 64 + ((quad ^ ((l16 >> 1) & 3)) << 4);
    const char* rdA = smem + (wm << 12) + rowo;            // + i*1024 + bufo
    const char* rdB = smem + 16384 + (wn << 12) + rowo;    // + j*1024 + bufo

#define STG3(BO) do { gld16(pa0, stA + (BO)); gld16(pa1, stA + (BO) + 8192);   \
                      gld16(pb0, stB + (BO));                                  \
                      pa0 += 32; pa1 += 32; pb0 += 32; } while (0)

    STG3(0);
    if (nkt > 1) {
        STG3(24576);
        asm volatile("s_waitcnt vmcnt(3)" ::: "memory");
    } else {
        asm volatile("s_waitcnt vmcnt(0)" ::: "memory");
    }
    __builtin_amdgcn_s_barrier();

    int ro = 0, so = 49152;
    for (int kt = 0; kt < nkt; ++kt) {
        const char* ra = rdA + ro;
        const char* rb = rdB + ro;
        bf16x8 a0 = *(const bf16x8*)(ra);
        bf16x8 a1 = *(const bf16x8*)(ra + 1024);
        bf16x8 a2 = *(const bf16x8*)(ra + 2048);
        bf16x8 a3 = *(const bf16x8*)(ra + 3072);
        bf16x8 b0 = *(const bf16x8*)(rb);
        bf16x8 b1 = *(const bf16x8*)(rb + 1024);
        bf16x8 b2 = *(const bf16x8*)(rb + 2048);
        bf16x8 b3 = *(const bf16x8*)(rb + 3072);
        const bool st = (kt + 2) < nkt;
        if (st) STG3(so);
        asm volatile("s_waitcnt lgkmcnt(0)" ::: "memory");
        __builtin_amdgcn_sched_barrier(0);
        __builtin_amdgcn_s_setprio(1);
        MMR(a0, 0); MMR(a1, 1); MMR(a2, 2); MMR(a3, 3);
        __builtin_amdgcn_s_setprio(0);
        if (st) asm volatile("s_waitcnt vmcnt(3)" ::: "memory");
        else    asm volatile("s_waitcnt vmcnt(0)" ::: "memory");
        __builtin_amdgcn_s_barrier();
        ro = (ro == 49152) ? 0 : (ro + 24576);
        so = (so == 49152) ? 0 : (so + 24576);
    }
#undef STG3
}

// ---------------------------------------------------------------------------
__global__ __launch_bounds__(256)
void convert_x_kernel(const float* __restrict__ x, bf16_t* __restrict__ xb)
{
    const size_t i = ((size_t)blockIdx.x * 256 + threadIdx.x) * 8;
    float4 a = *(const float4*)&x[i];
    float4 b = *(const float4*)&x[i + 4];
    bf16x8 o;
    o[0] = (bf16_t)a.x; o[1] = (bf16_t)a.y; o[2] = (bf16_t)a.z; o[3] = (bf16_t)a.w;
    o[4] = (bf16_t)b.x; o[5] = (bf16_t)b.y; o[6] = (bf16_t)b.z; o[7] = (bf16_t)b.w;
    *(bf16x8*)&xb[i] = o;
}

// All three W [1024x1024] fp32 -> WT bf16 transposed, z selects matrix
__global__ __launch_bounds__(256)
void transpose_w_kernel(const float* __restrict__ W0, const float* __restrict__ W1,
                        const float* __restrict__ W2, bf16_t* __restrict__ WT)
{
    __shared__ float t[32][33];
    const float* W = (blockIdx.z == 0) ? W0 : (blockIdx.z == 1) ? W1 : W2;
    bf16_t* WTz = WT + (size_t)blockIdx.z * 1024 * 1024;
    const int k0 = blockIdx.y * 32, n0 = blockIdx.x * 32;
    const int r = threadIdx.x >> 3, c4 = (threadIdx.x & 7) * 4;
    float4 v = *(const float4*)&W[(size_t)(k0 + r) * 1024 + n0 + c4];
    t[r][c4 + 0] = v.x; t[r][c4 + 1] = v.y; t[r][c4 + 2] = v.z; t[r][c4 + 3] = v.w;
    __syncthreads();
    bf16x4 o;
#pragma unroll
    for (int j = 0; j < 4; ++j) o[j] = (bf16_t)t[c4 + j][r];
    *(bf16x4*)&WTz[(size_t)(n0 + r) * 1024 + k0 + c4] = o;
}

// ---------------------------------------------------------------------------
// QK projection: C[M,2048] bf16 = xb[M,1024] x WT[2048,1024]^T + (bq|bk)
// 256x256 tiles, 256 blocks = 1/CU, bijective XCD chunking.
// ---------------------------------------------------------------------------
__global__ __launch_bounds__(512, 2)
void gemm_qk256(const bf16_t* __restrict__ A, const bf16_t* __restrict__ Bt,
                const float* __restrict__ bq, const float* __restrict__ bk,
                bf16_t* __restrict__ C, int N, int Kd)
{
    __shared__ __align__(16) char smem[98304];
    int bid = blockIdx.y * 8 + blockIdx.x;          // 256 blocks
    bid = (bid & 7) * 32 + (bid >> 3);              // XCD chunking (256%8==0)
    const int n0 = (bid & 7) * 256;
    const int m0 = (bid >> 3) * 256;
    const int tid = threadIdx.x;

    f32x4 acc[8][4];
#pragma unroll
    for (int i = 0; i < 8; ++i)
#pragma unroll
        for (int j = 0; j < 4; ++j) acc[i][j] = (f32x4)(0.0f);

    ml256x256(A + (size_t)m0 * Kd, Bt + (size_t)n0 * Kd, Kd, Kd, Kd >> 5,
              smem, tid, acc);

    const int w = tid >> 6, lane = tid & 63;
    const int wm = w & 1, wn = w >> 1, quad = lane >> 4, l16 = lane & 15;
#pragma unroll
    for (int j = 0; j < 4; ++j) {
        const int col = n0 + wn * 64 + j * 16 + l16;
        const float bval = (col < 1024) ? bq[col] : bk[col - 1024];
#pragma unroll
        for (int i = 0; i < 8; ++i) {
            const int row = m0 + wm * 128 + i * 16 + quad * 4;
#pragma unroll
            for (int r = 0; r < 4; ++r)
                C[(size_t)(row + r) * N + col] = (bf16_t)(acc[i][j][r] + bval);
        }
    }
}

// ---------------------------------------------------------------------------
// V^T projection: VT[1024, 8192] = WvT[1024,1024] x xb[8192,1024]^T + bv
// 256x128 tiles -> 4x64 = 256 blocks, XCD chunking.
// ---------------------------------------------------------------------------
__global__ __launch_bounds__(512, 2)
void gemm_vt256(const bf16_t* __restrict__ WvT, const bf16_t* __restrict__ xb,
                const float* __restrict__ bv, bf16_t* __restrict__ VT,
                int N, int Kd)
{
    __shared__ __align__(16) char smem[73728];
    int bid = blockIdx.y * 64 + blockIdx.x;         // 256 blocks
    bid = (bid & 7) * 32 + (bid >> 3);              // XCD chunking
    const int m0 = (bid >> 6) * 256;     // d
    const int n0 = (bid & 63) * 128;     // b*L + l
    const int tid = threadIdx.x;

    f32x4 acc[4][4];
#pragma unroll
    for (int i = 0; i < 4; ++i)
#pragma unroll
        for (int j = 0; j < 4; ++j) acc[i][j] = (f32x4)(0.0f);

    ml256x128(WvT + (size_t)m0 * Kd, xb + (size_t)n0 * Kd, Kd, Kd, Kd >> 5,
              smem, tid, acc);

    const int w = tid >> 6, lane = tid & 63;
    const int wm = w & 3, wn = w >> 2, quad = lane >> 4, l16 = lane & 15;
#pragma unroll
    for (int i = 0; i < 4; ++i) {
        const int row = m0 + wm * 64 + i * 16 + quad * 4;    // d index
#pragma unroll
        for (int r = 0; r < 4; ++r) {
            const float bval = bv[row + r];
#pragma unroll
            for (int j = 0; j < 4; ++j) {
                const int col = n0 + wn * 64 + j * 16 + l16;
                VT[(size_t)(row + r) * N + col] = (bf16_t)(acc[i][j][r] + bval);
            }
        }
    }
}

// ---------------------------------------------------------------------------
// Scores: 256x256 triangular tiles, 36/batch -> 144 blocks (one round, 1/CU).
// ---------------------------------------------------------------------------
__global__ __launch_bounds__(512, 2)
void scores256(const bf16_t* __restrict__ Q, const bf16_t* __restrict__ K,
               int ldq, const int* __restrict__ lengths,
               float* __restrict__ S, int L, int Dd, float alpha)
{
    __shared__ __align__(16) char smem[98304];
    const int b = blockIdx.z;
    const int len = lengths[b];
    int it = 0;
    while ((it + 1) * (it + 2) / 2 <= (int)blockIdx.x) ++it;
    const int jt = blockIdx.x - it * (it + 1) / 2;
    const int m0 = it * 256, n0 = jt * 256;
    float* Sb = S + (size_t)b * L * L;
    const int tid = threadIdx.x;

    f32x4 acc[8][4];
#pragma unroll
    for (int i = 0; i < 8; ++i)
#pragma unroll
        for (int j = 0; j < 4; ++j) acc[i][j] = (f32x4)(0.0f);

    const bf16_t* Qb = Q + (size_t)b * L * ldq + (size_t)m0 * ldq;
    const bf16_t* Kb = K + (size_t)b * L * ldq + (size_t)n0 * ldq;
    ml256x256(Qb, Kb, ldq, ldq, Dd >> 5, smem, tid, acc);

    const int w = tid >> 6, lane = tid & 63;
    const int wm = w & 1, wn = w >> 1, quad = lane >> 4, l16 = lane & 15;
#pragma unroll
    for (int i = 0; i < 8; ++i) {
#pragma unroll
        for (int j = 0; j < 4; ++j) {
            const int col = n0 + wn * 64 + j * 16 + l16;
#pragma unroll
            for (int r = 0; r < 4; ++r) {
                const int row = m0 + wm * 128 + i * 16 + quad * 4 + r;
                float s = acc[i][j][r] * alpha;
                if (col > row) s += NEGV;                 // causal first
                if (row >= len || col >= len) s += NEGV;  // then length mask
                Sb[(size_t)row * L + col] = s;
            }
        }
    }
}

// ---------------------------------------------------------------------------
// Row softmax, causally bounded: values for j<bound (128-aligned), ZEROS for
// j in [bound, bound2) with bound2 256-aligned -- pv consumes P in 256-row
// k-extents and must never read garbage.
// ---------------------------------------------------------------------------
__global__ __launch_bounds__(256)
void softmax_kernel(const float* __restrict__ S, bf16_t* __restrict__ P,
                    int L, int ldp)
{
    __shared__ float red[8];
    const int i = blockIdx.x;
    const int bound  = ((i >> 7) + 1) << 7;
    const int bound2 = ((i >> 8) + 1) << 8;
    const float* row = S + ((size_t)blockIdx.y * L + i) * L;
    bf16_t* prow = P + ((size_t)blockIdx.y * L + i) * ldp;
    const int t = threadIdx.x;
    const int w = t >> 6, lane = t & 63;
    const int j8 = t * 8;
    const bool act = j8 < bound;

    float v[8];
    float m = -3.0e38f;
    if (act) {
        float4 a = *(const float4*)&row[j8];
        float4 b = *(const float4*)&row[j8 + 4];
        v[0] = a.x; v[1] = a.y; v[2] = a.z; v[3] = a.w;
        v[4] = b.x; v[5] = b.y; v[6] = b.z; v[7] = b.w;
#pragma unroll
        for (int j = 0; j < 8; ++j) m = fmaxf(m, v[j]);
    }
#pragma unroll
    for (int off = 32; off > 0; off >>= 1) m = fmaxf(m, __shfl_down(m, off, 64));
    if (lane == 0) red[w] = m;
    __syncthreads();
    m = fmaxf(fmaxf(red[0], red[1]), fmaxf(red[2], red[3]));

    float s = 0.f;
    if (act) {
#pragma unroll
        for (int j = 0; j < 8; ++j) {
            v[j] = __expf(v[j] - m);
            s += v[j];
        }
    }
#pragma unroll
    for (int off = 32; off > 0; off >>= 1) s += __shfl_down(s, off, 64);
    if (lane == 0) red[4 + w] = s;
    __syncthreads();
    s = red[4] + red[5] + red[6] + red[7];

    if (act) {
        const float inv = 1.0f / s;
        bf16x8 o;
#pragma unroll
        for (int j = 0; j < 8; ++j) o[j] = (bf16_t)(v[j] * inv);
        *(bf16x8*)&prow[j8] = o;
    } else if (j8 < bound2) {
        bf16x8 z;
#pragma unroll
        for (int j = 0; j < 8; ++j) z[j] = (bf16_t)0.0f;
        *(bf16x8*)&prow[j8] = z;
    }
}

// ---------------------------------------------------------------------------
// PV: O[b][L,D] fp32 = P[b][L,L] x V^T (VT layout [d][b][l], ld 8192).
// 256(l) x 128(d) tiles -> 256 blocks, causal k-limit at 256-row granularity,
// heavy m-tiles first, XCD chunking within batch.
// ---------------------------------------------------------------------------
__global__ __launch_bounds__(512, 2)
void pv256(const bf16_t* __restrict__ P, int ldp,
           const bf16_t* __restrict__ VT, int ldv,
           float* __restrict__ O, int L, int Dd)
{
    __shared__ __align__(16) char smem[73728];
    const int b = blockIdx.z;
    int bid = blockIdx.y * 8 + blockIdx.x;       // 64 per batch
    bid = (bid & 7) * 8 + (bid >> 3);            // XCD chunking
    const int mt = 7 - (bid >> 3);               // heavy first
    const int m0 = mt * 256, n0 = (bid & 7) * 128;
    const int tid = threadIdx.x;

    f32x4 acc[4][4];
#pragma unroll
    for (int i = 0; i < 4; ++i)
#pragma unroll
        for (int j = 0; j < 4; ++j) acc[i][j] = (f32x4)(0.0f);

    const int nkt = (m0 + 256) >> 5;   // P[i][j]==0 for j >= roundup(i+1,256)
    const bf16_t* Pb = P + (size_t)b * L * ldp + (size_t)m0 * ldp;
    const bf16_t* Vb = VT + (size_t)b * L + (size_t)n0 * ldv;
    ml256x128(Pb, Vb, ldp, ldv, nkt, smem, tid, acc);

    float* Ob = O + (size_t)b * L * Dd;
    const int w = tid >> 6, lane = tid & 63;
    const int wm = w & 3, wn = w >> 2, quad = lane >> 4, l16 = lane & 15;
#pragma unroll
    for (int i = 0; i < 4; ++i) {
        const int row = m0 + wm * 64 + i * 16 + quad * 4;
#pragma unroll
        for (int j = 0; j < 4; ++j) {
            const int col = n0 + wn * 64 + j * 16 + l16;
#pragma unroll
            for (int r = 0; r < 4; ++r)
                Ob[(size_t)(row + r) * Dd + col] = acc[i][j][r];
        }
    }
}

// ---------------------------------------------------------------------------
extern "C" void kernel_launch(void* const* d_in, const int* in_sizes, int n_in,
                              void* d_out, int out_size, void* d_ws, size_t ws_size,
                              hipStream_t stream)
{
    const float* x  = (const float*)d_in[0];
    const float* Wq = (const float*)d_in[1];
    const float* bq = (const float*)d_in[2];
    const float* Wk = (const float*)d_in[3];
    const float* bk = (const float*)d_in[4];
    const float* Wv = (const float*)d_in[5];
    const float* bv = (const float*)d_in[6];
    const int*  len = (const int*)d_in[7];
    float* out = (float*)d_out;

    const int B = 4, L = 2048, D = 1024;
    const int M = B * L;     // 8192
    const int N2 = 2 * D;    // 2048

    // Workspace (140.5 MB):
    //  xb [8192][1024] bf16 = 16 MB
    //  WT [3072][1024] bf16 = 6 MB   (Wq^T | Wk^T | Wv^T)
    //  QK [8192][2048] bf16 = 32 MB  (cols 0:Q 1024:K; rows reused as P, ld 2048)
    //  VT [1024][8192] bf16 = 16 MB  (layout [d][b][l])
    //  S  [4][2048][2048] fp32 = 64 MB (lower-triangular tiles only)
    bf16_t* xb = (bf16_t*)d_ws;
    bf16_t* WT = xb + (size_t)M * D;
    bf16_t* QK = WT + (size_t)3 * D * D;
    bf16_t* VT = QK + (size_t)M * N2;
    float*  S  = (float*)(VT + (size_t)D * M);
    bf16_t* P  = QK;   // alias: Q,K dead after scores; ld = 2048

    // 1) x -> bf16
    convert_x_kernel<<<(M * D) / 2048, 256, 0, stream>>>(x, xb);

    // 2) all W transposes in one launch
    transpose_w_kernel<<<dim3(32, 32, 3), 256, 0, stream>>>(Wq, Wk, Wv, WT);

    // 3) QK projection (N=2048), 256x256 tiles, 256 blocks
    gemm_qk256<<<dim3(8, 32), 512, 0, stream>>>(xb, WT, bq, bk, QK, N2, D);

    // 4) V^T projection, 256x128 tiles, 256 blocks
    gemm_vt256<<<dim3(64, 4), 512, 0, stream>>>(
        WT + (size_t)2 * D * D, xb, bv, VT, M, D);

    // 5) scores, triangular 256x256 tiles, 144 blocks
    scores256<<<dim3(36, 1, B), 512, 0, stream>>>(
        QK, QK + 1024, N2, len, S, L, D, 0.03125f);

    // 6) bounded softmax -> P (aliased over QK rows), zero-filled to 256 bound
    softmax_kernel<<<dim3(L, B), 256, 0, stream>>>(S, P, L, N2);

    // 7) O = P @ V, causal k-limit, 256 blocks, heavy tiles first
    pv256<<<dim3(8, 8, 4), 512, 0, stream>>>(P, N2, VT, M, out, L, D);
}